// Round 7
// baseline (7052.358 us; speedup 1.0000x reference)
//
#include <hip/hip_runtime.h>
#include <hip/hip_fp16.h>

typedef float2 cplx;
typedef __half2 gpak;   // packed complex fp16 (re, im)

constexpr int B_   = 2;
constexpr int C_   = 12;
constexpr int NR   = 96;
constexpr int NC_  = 96;
constexpr int NS   = 48;
constexpr int NP   = 288;
constexpr int NCOL = NC_ * NS;      // 4608
constexpr int NVOX = NR * NCOL;     // 442368
constexpr int TILE = 64;            // cols per k_fwd/k_inv block (256-B bursts)
constexpr int TILES = NCOL / TILE;  // 72
constexpr int LSTR = 49;            // padded nc stride in k_plane LDS
constexpr int CPB  = 3;             // coils per k_inv block
constexpr float PI2 = 6.28318530717958647692f;
constexpr float R96 = 1.f/96.f, R48 = 1.f/48.f, R288 = 1.f/288.f;

// scalar slot map (floats, sc = 512 B): RTR(it)=8+2it+b, PAP(it)=32+2it+b, PN(it)=52+2it+b
#define RTR(it) (8 + 2*(it))
#define PAP(it) (32 + 2*(it))
#define PN(it)  (52 + 2*(it))

__device__ inline cplx cmulc(cplx a, cplx b){ return make_float2(a.x*b.x - a.y*b.y, a.x*b.y + a.y*b.x); }
__device__ inline cplx cmuljc(cplx a, cplx b){ return make_float2(a.x*b.x + a.y*b.y, a.y*b.x - a.x*b.y); }
__device__ inline cplx caddc(cplx a, cplx b){ return make_float2(a.x+b.x, a.y+b.y); }
__device__ inline cplx csubc(cplx a, cplx b){ return make_float2(a.x-b.x, a.y-b.y); }

__device__ __forceinline__ gpak pack_g(cplx v){ return __float22half2_rn(v); }
__device__ __forceinline__ cplx unpack_g(gpak h){ return __half22float2(h); }

__device__ inline void atomAddF(float* p, float v){
    __hip_atomic_fetch_add(p, v, __ATOMIC_RELAXED, __HIP_MEMORY_SCOPE_AGENT);
}

__device__ __forceinline__ cplx twf(float k, float rN){
    float s, c; __sincosf(-PI2 * k * rN, &s, &c);
    return make_float2(c, s);
}

// ---------------- register DFT cores ----------------
template<bool INV>
__device__ __forceinline__ cplx w16k(int k){
    constexpr float re[10] = {1.f, 0.92387953251f, 0.70710678119f, 0.38268343236f, 0.f,
                              -0.38268343236f, -0.70710678119f, -0.92387953251f, -1.f, -0.92387953251f};
    constexpr float im[10] = {0.f, -0.38268343236f, -0.70710678119f, -0.92387953251f, -1.f,
                              -0.92387953251f, -0.70710678119f, -0.38268343236f, 0.f, 0.38268343236f};
    return make_float2(re[k], INV ? -im[k] : im[k]);
}
template<bool INV>
__device__ __forceinline__ cplx w6k(int k){
    const float rr = (k == 1) ? 0.5f : -0.5f;
    const float ii = INV ? 0.86602540378f : -0.86602540378f;
    return make_float2(rr, ii);
}
template<bool INV>
__device__ __forceinline__ void r4(cplx& a0, cplx& a1, cplx& a2, cplx& a3){
    cplx t0 = caddc(a0, a2), t1 = csubc(a0, a2);
    cplx t2 = caddc(a1, a3), t3 = csubc(a1, a3);
    cplx it3 = INV ? make_float2(-t3.y, t3.x) : make_float2(t3.y, -t3.x);
    a0 = caddc(t0, t2); a1 = caddc(t1, it3);
    a2 = csubc(t0, t2); a3 = csubc(t1, it3);
}
template<bool INV>
__device__ __forceinline__ void r3(cplx& a0, cplx& a1, cplx& a2){
    cplx t1 = caddc(a1, a2), t2 = csubc(a1, a2);
    cplx m1 = make_float2(a0.x - 0.5f * t1.x, a0.y - 0.5f * t1.y);
    const float s3 = INV ? -0.8660254037844386f : 0.8660254037844386f;
    cplx b1 = make_float2(m1.x + s3 * t2.y, m1.y - s3 * t2.x);
    cplx b2 = make_float2(m1.x - s3 * t2.y, m1.y + s3 * t2.x);
    a0 = caddc(a0, t1); a1 = b1; a2 = b2;
}
template<bool INV>
__device__ __forceinline__ void dft16(cplx x[16]){
    cplx y[16];
    #pragma unroll
    for (int j = 0; j < 4; ++j){
        cplx a0 = x[j], a1 = x[j+4], a2 = x[j+8], a3 = x[j+12];
        r4<INV>(a0, a1, a2, a3);
        y[4*j+0] = a0;
        y[4*j+1] = (j == 0) ? a1 : cmulc(a1, w16k<INV>(j));
        y[4*j+2] = (j == 0) ? a2 : cmulc(a2, w16k<INV>(2*j));
        y[4*j+3] = (j == 0) ? a3 : cmulc(a3, w16k<INV>(3*j));
    }
    #pragma unroll
    for (int q = 0; q < 4; ++q){
        cplx a0 = y[q], a1 = y[q+4], a2 = y[q+8], a3 = y[q+12];
        r4<INV>(a0, a1, a2, a3);
        x[q] = a0; x[q+4] = a1; x[q+8] = a2; x[q+12] = a3;
    }
}
template<bool INV>
__device__ __forceinline__ void dft6(cplx x[6]){
    cplx y[6];
    { cplx a0 = x[0], a1 = x[2], a2 = x[4]; r3<INV>(a0, a1, a2); y[0] = a0; y[1] = a1; y[2] = a2; }
    { cplx a0 = x[1], a1 = x[3], a2 = x[5]; r3<INV>(a0, a1, a2);
      y[3] = a0; y[4] = cmulc(a1, w6k<INV>(1)); y[5] = cmulc(a2, w6k<INV>(2)); }
    #pragma unroll
    for (int q = 0; q < 3; ++q){
        cplx s = caddc(y[q], y[q+3]), d = csubc(y[q], y[q+3]);
        x[q] = s; x[q+3] = d;
    }
}

template<int NW>
__device__ inline float block_reduce(float v){
    #pragma unroll
    for (int o = 32; o >= 1; o >>= 1) v += __shfl_down(v, o, 64);
    __shared__ float sh[NW];
    const int lane = threadIdx.x & 63, wv = threadIdx.x >> 6;
    if (lane == 0) sh[wv] = v;
    __syncthreads();
    float s = 0.f;
    if (threadIdx.x == 0){
        #pragma unroll
        for (int w = 0; w < NW; ++w) s += sh[w];
    }
    return s;
}

// ---------------------------------------------------------------------------
// K1: coil = csh*ph (fp16 in), padded row FFT 96->288 via DIF 6x16.
// Products register-cached across the 3 a-slices (globals read ONCE).
// 64-col tiles -> all g stores are aligned 256-B bursts.
// ---------------------------------------------------------------------------
__global__ __launch_bounds__(512, 4)
void k_fwd(const gpak* __restrict__ ph, const gpak* __restrict__ csh,
           gpak* __restrict__ g, int cg0, int ncg, int ncga)
{
    __shared__ cplx A[NR * TILE];   // 96 x 64, col-contiguous accesses only
    const int tid = threadIdx.x, bid = blockIdx.x;
    const int tile = bid % TILES;
    const int rem = bid / TILES;
    const int gc = rem % ncg, b = rem / ncg, c = cg0 + gc;
    const int colbase = tile * TILE;
    const gpak* pp = ph  + (size_t)b * NVOX;
    const gpak* cs = csh + ((size_t)b * C_ + c) * NVOX;
    gpak* gg = g + (size_t)(b * ncga + gc) * ((size_t)NP * NCOL);

    cplx xr[2][6];
    #pragma unroll
    for (int it = 0; it < 2; ++it){
        const int id = tid + it * 512;
        const int m = id >> 6, col = id & 63;
        #pragma unroll
        for (int v = 0; v < 6; ++v){
            const int gi = (m + 16*v) * NCOL + colbase + col;
            xr[it][v] = cmulc(unpack_g(pp[gi]), unpack_g(cs[gi]));
        }
    }

    for (int a = 0; a < 3; ++a){
        if (a) __syncthreads();
        #pragma unroll
        for (int it = 0; it < 2; ++it){
            const int id = tid + it * 512;
            const int m = id >> 6, col = id & 63;
            cplx xv[6];
            if (a){
                cplx t = twf((float)(a*m), R288);
                const cplx stp = twf((float)(16*a), R288);
                #pragma unroll
                for (int v = 0; v < 6; ++v){ xv[v] = cmulc(xr[it][v], t); t = cmulc(t, stp); }
            } else {
                #pragma unroll
                for (int v = 0; v < 6; ++v) xv[v] = xr[it][v];
            }
            dft6<false>(xv);
            cplx* dst = &A[m * TILE + col];
            dst[0] = xv[0];
            const cplx w1 = twf((float)m, R96);
            cplx t = w1;
            #pragma unroll
            for (int r = 1; r < 6; ++r){ dst[16*r*TILE] = cmulc(xv[r], t); t = cmulc(t, w1); }
        }
        __syncthreads();
        if (tid < 384){
            const int r = tid >> 6, col = tid & 63;
            cplx d[16];
            #pragma unroll
            for (int m = 0; m < 16; ++m) d[m] = A[(m + 16*r) * TILE + col];
            dft16<false>(d);
            const cplx pref = twf((float)(32*a), R96);   // e^{-2pi i a/3}
            #pragma unroll
            for (int t = 0; t < 16; ++t)
                gg[(size_t)(18*t + 3*r + a) * NCOL + colbase + col] = pack_g(cmulc(d[t], pref));
        }
    }
}

// ---------------------------------------------------------------------------
// K2: per padded row: g <- conj(w) * IFFT2( pm * FFT2( w*g ) ), DIF->DIT,
// permuted mask, in-place passes, turnaround fused in registers; g,w fp16.
// ---------------------------------------------------------------------------
__global__ __launch_bounds__(512, 4)
void k_plane(gpak* __restrict__ g, const gpak* __restrict__ wh,
             const float* __restrict__ pm3, int ncg, int ncga)
{
    __shared__ cplx A[NC_ * LSTR];
    const int tid = threadIdx.x, bid = blockIdx.x;
    const int rp = bid % NP;
    const int rem = bid / NP;
    const int gc = rem % ncg, b = rem / ncg;
    gpak* gg = g + ((size_t)(b * ncga + gc) * NP + rp) * NCOL;
    const gpak*  wp  = wh  + ((size_t)b * NP + rp) * NCOL;
    const float* pmv = pm3 + ((size_t)b * NP + rp) * NCOL;

    // ph1: ns DIF p1 (radix-3) from global, x w
    #pragma unroll
    for (int it = 0; it < 3; ++it){
        const int id = tid + it * 512;
        const int m = id & 15, nc = id >> 4;
        cplx xv[3];
        #pragma unroll
        for (int v = 0; v < 3; ++v){
            const int e = nc * NS + m + 16*v;
            xv[v] = cmulc(unpack_g(gg[e]), unpack_g(wp[e]));
        }
        r3<false>(xv[0], xv[1], xv[2]);
        cplx* dst = &A[nc * LSTR + m];
        const cplx w1 = twf((float)m, R48);
        dst[0]  = xv[0];
        dst[16] = cmulc(xv[1], w1);
        dst[32] = cmulc(xv[2], cmulc(w1, w1));
    }
    __syncthreads();
    // ph2: ns DIF p2 (radix-16, contiguous, in place)
    if (tid < 288){
        const int rho = tid / 96, nc = tid - rho * 96;
        cplx* pA = &A[nc * LSTR + 16 * rho];
        cplx d[16];
        #pragma unroll
        for (int m = 0; m < 16; ++m) d[m] = pA[m];
        dft16<false>(d);
        #pragma unroll
        for (int t = 0; t < 16; ++t) pA[t] = d[t];
    }
    __syncthreads();
    // ph3: nc DIF p1 (radix-6, in place)
    #pragma unroll
    for (int it = 0; it < 2; ++it){
        const int id = tid + it * 512;
        if (id < 768){
            const int m = id / NS, ns = id - m * NS;
            cplx xv[6];
            #pragma unroll
            for (int v = 0; v < 6; ++v) xv[v] = A[(m + 16*v) * LSTR + ns];
            dft6<false>(xv);
            const cplx w1 = twf((float)m, R96);
            A[m * LSTR + ns] = xv[0];
            cplx t = w1;
            #pragma unroll
            for (int r = 1; r < 6; ++r){ A[(m + 16*r) * LSTR + ns] = cmulc(xv[r], t); t = cmulc(t, w1); }
        }
    }
    __syncthreads();
    // ph4: nc DIF p2 + permuted mask + nc DIT p2 — in registers
    if (tid < 288){
        const int r = tid / NS, ns = tid - r * NS;
        cplx d[16];
        #pragma unroll
        for (int m = 0; m < 16; ++m) d[m] = A[(m + 16*r) * LSTR + ns];
        dft16<false>(d);
        #pragma unroll
        for (int t = 0; t < 16; ++t){
            const float mval = pmv[(6*t + r) * NS + ns];
            d[t].x *= mval; d[t].y *= mval;
        }
        dft16<true>(d);
        #pragma unroll
        for (int m = 0; m < 16; ++m) A[(m + 16*r) * LSTR + ns] = d[m];
    }
    __syncthreads();
    // ph5: nc DIT p1 (undo radix-6, in place)
    #pragma unroll
    for (int it = 0; it < 2; ++it){
        const int id = tid + it * 512;
        if (id < 768){
            const int m = id / NS, ns = id - m * NS;
            cplx xv[6];
            const cplx w1 = twf(-(float)m, R96);
            cplx t = make_float2(1.f, 0.f);
            #pragma unroll
            for (int r = 0; r < 6; ++r){ xv[r] = cmulc(A[(m + 16*r) * LSTR + ns], t); t = cmulc(t, w1); }
            dft6<true>(xv);
            #pragma unroll
            for (int v = 0; v < 6; ++v) A[(m + 16*v) * LSTR + ns] = xv[v];
        }
    }
    __syncthreads();
    // ph6: ns DIT p2 (idft16 contiguous, in place)
    if (tid < 288){
        const int rho = tid / 96, nc = tid - rho * 96;
        cplx* pA = &A[nc * LSTR + 16 * rho];
        cplx d[16];
        #pragma unroll
        for (int t = 0; t < 16; ++t) d[t] = pA[t];
        dft16<true>(d);
        #pragma unroll
        for (int m = 0; m < 16; ++m) pA[m] = d[m];
    }
    __syncthreads();
    // ph7: ns DIT p1 (undo radix-3) x conj(w), store fp16
    #pragma unroll
    for (int it = 0; it < 3; ++it){
        const int id = tid + it * 512;
        const int m = id & 15, nc = id >> 4;
        const cplx w1 = twf(-(float)m, R48);
        cplx xv[3];
        xv[0] = A[nc * LSTR + m];
        xv[1] = cmulc(A[nc * LSTR + m + 16], w1);
        xv[2] = cmulc(A[nc * LSTR + m + 32], cmulc(w1, w1));
        r3<true>(xv[0], xv[1], xv[2]);
        #pragma unroll
        for (int v = 0; v < 3; ++v){
            const int e = nc * NS + m + 16*v;
            gg[e] = pack_g(cmuljc(xv[v], unpack_g(wp[e])));
        }
    }
}

// ---------------------------------------------------------------------------
// K3: row IFFT 288->96 (crop) via DIT 16x6 per a-slice, 3 coils per block;
// conj(csm) folded in; one atomic sweep into ap; per-block pAp partial.
// ---------------------------------------------------------------------------
__global__ __launch_bounds__(512, 4)
void k_inv(const gpak* __restrict__ g, const gpak* __restrict__ csh,
           const gpak* __restrict__ ph, float* __restrict__ ap,
           float* __restrict__ sc, int cg0, int ncg, int ng, int ncga, int iter)
{
    __shared__ cplx A[NR * TILE];
    const int tid = threadIdx.x, bid = blockIdx.x;
    const int tile = bid % TILES;
    const int rem = bid / TILES;
    const int gl = rem % ng, b = rem / ng;
    const int cbase = cg0 + gl * CPB;
    const int cnum = (ncg - gl * CPB) < CPB ? (ncg - gl * CPB) : CPB;
    const int colbase = tile * TILE;

    cplx accT[2][6];
    #pragma unroll
    for (int it = 0; it < 2; ++it)
        #pragma unroll
        for (int j = 0; j < 6; ++j) accT[it][j] = make_float2(0.f, 0.f);

    bool first = true;
    for (int ci = 0; ci < cnum; ++ci){
        const int c = cbase + ci;
        const gpak* gc_ = g + (size_t)(b * ncga + (c - cg0)) * ((size_t)NP * NCOL);
        const gpak* cs  = csh + ((size_t)b * C_ + c) * NVOX;

        for (int a = 0; a < 3; ++a){
            if (!first) __syncthreads();
            first = false;
            if (tid < 384){
                const int c6 = tid >> 6, col = tid & 63;
                cplx d[16];
                #pragma unroll
                for (int u = 0; u < 16; ++u)
                    d[u] = unpack_g(gc_[(size_t)(3*(c6 + 6*u) + a) * NCOL + colbase + col]);
                dft16<true>(d);
                #pragma unroll
                for (int q = 0; q < 16; ++q) A[(c6 + 6*q) * TILE + col] = d[q];
            }
            __syncthreads();
            #pragma unroll
            for (int it = 0; it < 2; ++it){
                const int id = tid + it * 512;
                const int q = id >> 6, col = id & 63;
                cplx xv[6];
                const cplx w1 = twf(-(float)q, R96);
                cplx t = make_float2(1.f, 0.f);
                #pragma unroll
                for (int cc = 0; cc < 6; ++cc){ xv[cc] = cmulc(A[(cc + 6*q) * TILE + col], t); t = cmulc(t, w1); }
                dft6<true>(xv);
                cplx f = twf(-(float)(a * (q + 96)), R288);
                f.x *= (1.f/288.f); f.y *= (1.f/288.f);
                const cplx fs = twf(-(float)(16 * a), R288);
                #pragma unroll
                for (int j = 0; j < 6; ++j){
                    const int gi = (q + 16*j) * NCOL + colbase + col;
                    accT[it][j] = caddc(accT[it][j], cmuljc(cmulc(xv[j], f), unpack_g(cs[gi])));
                    f = cmulc(f, fs);
                }
            }
        }
    }
    // epilogue: atomics into ap + local pAp partial
    float* apb = ap + (size_t)b * NVOX * 2;
    const gpak* pb = ph + (size_t)b * NVOX;
    float dotloc = 0.f;
    #pragma unroll
    for (int it = 0; it < 2; ++it){
        const int id = tid + it * 512;
        const int q = id >> 6, col = id & 63;
        #pragma unroll
        for (int j = 0; j < 6; ++j){
            const int gi = (q + 16*j) * NCOL + colbase + col;
            atomAddF(&apb[2 * gi],     accT[it][j].x);
            atomAddF(&apb[2 * gi + 1], accT[it][j].y);
            const cplx pv = unpack_g(pb[gi]);
            dotloc += pv.x * accT[it][j].x + pv.y * accT[it][j].y;
        }
    }
    const float s = block_reduce<8>(dotloc);
    if (tid == 0) atomAddF(&sc[PAP(iter) + b], s);
}

// ---------------------------------------------------------------------------
// prep kernels (once per solve)
// ---------------------------------------------------------------------------
__global__ __launch_bounds__(512)
void k_prep_csm(const cplx* __restrict__ csm, gpak* __restrict__ csh, int n)
{
    for (int i = blockIdx.x * 512 + threadIdx.x; i < n; i += gridDim.x * 512)
        csh[i] = pack_g(csm[i]);
}

__global__ __launch_bounds__(512)
void k_prep_wm(const cplx* __restrict__ wpsf, const float* __restrict__ mask,
               gpak* __restrict__ wh, float* __restrict__ pm3)
{
    const int bid = blockIdx.x;            // b*NP + rp
    const cplx*  wsrc = wpsf + (size_t)bid * NCOL;
    const float* mk   = mask + (size_t)bid * NCOL;
    gpak*  wdst = wh  + (size_t)bid * NCOL;
    float* out  = pm3 + (size_t)bid * NCOL;
    for (int e = threadIdx.x; e < NCOL; e += 512){
        wdst[e] = pack_g(wsrc[e]);
        const int knc = e / NS, pns = e - knc * NS;
        const int kns = 3 * (pns & 15) + (pns >> 4);
        out[e] = mk[knc * NS + kns] * (1.f / 4608.f);
    }
}

// ---------------------------------------------------------------------------
// CG kernels (slots-per-iteration; no k_dot sweep)
// ---------------------------------------------------------------------------
__global__ __launch_bounds__(256)
void k_rr0(const cplx* __restrict__ r, gpak* __restrict__ ph, float* __restrict__ sc)
{
    const int i = blockIdx.x * 256 + threadIdx.x;
    const int b = i / NVOX;
    const cplx rv = r[i];
    ph[i] = pack_g(rv);
    const float s = block_reduce<4>(rv.x*rv.x + rv.y*rv.y);
    if (threadIdx.x == 0){ atomAddF(&sc[RTR(0) + b], s); atomAddF(&sc[PN(0) + b], s); }
}

__global__ __launch_bounds__(256)
void k_update(cplx* __restrict__ x, cplx* __restrict__ r,
              const cplx* __restrict__ p, const cplx* __restrict__ ap,
              const float* __restrict__ lam1, float* __restrict__ sc, int it)
{
    const int i = blockIdx.x * 256 + threadIdx.x;
    const int b = i / NVOX;
    const float rtr = sc[RTR(it) + b];
    const bool act = rtr > 1e-5f;
    const float lam = lam1[0];
    const float alpha = rtr / (sc[PAP(it) + b] + lam * sc[PN(it) + b]);
    const cplx pv = p[i];
    cplx a = ap[i];
    a.x += lam * pv.x; a.y += lam * pv.y;
    cplx rv = r[i];
    if (act){
        cplx xv = x[i];
        xv.x += alpha * pv.x; xv.y += alpha * pv.y;
        x[i] = xv;
        rv.x -= alpha * a.x; rv.y -= alpha * a.y;
        r[i] = rv;
    }
    const float s = block_reduce<4>(rv.x*rv.x + rv.y*rv.y);
    if (threadIdx.x == 0) atomAddF(&sc[RTR(it+1) + b], s);
}

__global__ __launch_bounds__(256)
void k_pupd(cplx* __restrict__ p, gpak* __restrict__ ph,
            const cplx* __restrict__ r, float* __restrict__ sc, int it)
{
    const int i = blockIdx.x * 256 + threadIdx.x;
    const int b = i / NVOX;
    const float rtr = sc[RTR(it) + b];
    const bool act = rtr > 1e-5f;
    cplx pv = p[i];
    float loc;
    if (act){
        const float be = sc[RTR(it+1) + b] / rtr;
        const cplx rv = r[i];
        const cplx pn = make_float2(rv.x + be * pv.x, rv.y + be * pv.y);
        p[i] = pn; ph[i] = pack_g(pn);
        loc = pn.x*pn.x + pn.y*pn.y;
    } else {
        loc = pv.x*pv.x + pv.y*pv.y;
    }
    const float s = block_reduce<4>(loc);
    if (threadIdx.x == 0) atomAddF(&sc[PN(it+1) + b], s);
}

// ---------------------------------------------------------------------------
extern "C" void kernel_launch(void* const* d_in, const int* in_sizes, int n_in,
                              void* d_out, int out_size, void* d_ws, size_t ws_size,
                              hipStream_t stream)
{
    const cplx*  rhs  = (const cplx*)d_in[0];
    const cplx*  csm  = (const cplx*)d_in[1];
    const float* mask = (const float*)d_in[2];
    const cplx*  wpsf = (const cplx*)d_in[3];
    const float* lam1 = (const float*)d_in[4];

    const size_t vb   = (size_t)B_ * NVOX * sizeof(cplx);           // 7,077,888 B
    const size_t hv   = (size_t)B_ * NVOX * sizeof(gpak);           // 3.5 MB
    const size_t pmb  = (size_t)B_ * NP * NCOL * sizeof(float);     // 10.6 MB
    const size_t whb  = (size_t)B_ * NP * NCOL * sizeof(gpak);      // 10.6 MB
    const size_t cshb = (size_t)B_ * C_ * NVOX * sizeof(gpak);      // 42.5 MB
    const size_t percoil = (size_t)B_ * NP * NCOL * sizeof(gpak);   // 10.6 MB

    char* ws = (char*)d_ws;
    float* sc = (float*)ws;
    size_t off = 512;
    cplx* r    = (cplx*)(ws + off); off += vb;
    cplx* p    = (cplx*)(ws + off); off += vb;
    gpak* ph   = (gpak*)(ws + off); off += hv;
    float* pm3 = (float*)(ws + off); off += pmb;
    cplx* ap   = (cplx*)(ws + off); off += vb;
    gpak* csh  = (gpak*)(ws + off); off += cshb;
    gpak* wh   = (gpak*)(ws + off); off += whb;
    gpak* g    = (gpak*)(ws + off);
    cplx* x    = (cplx*)d_out;

    int ncga = 3;
    if (ws_size > off){
        size_t fit = (ws_size - off) / percoil;
        ncga = fit > (size_t)C_ ? C_ : (int)fit;
        ncga -= ncga % CPB;
        if (ncga < CPB) ncga = CPB;
    }

    hipMemsetAsync(d_out, 0, vb, stream);
    hipMemsetAsync(sc, 0, 512, stream);
    hipMemcpyAsync(r, rhs, vb, hipMemcpyDeviceToDevice, stream);
    hipMemcpyAsync(p, rhs, vb, hipMemcpyDeviceToDevice, stream);
    k_prep_csm<<<(B_ * C_ * NVOX) / 512, 512, 0, stream>>>(csm, csh, B_ * C_ * NVOX);
    k_prep_wm<<<B_ * NP, 512, 0, stream>>>(wpsf, mask, wh, pm3);
    k_rr0<<<(B_ * NVOX) / 256, 256, 0, stream>>>(r, ph, sc);

    for (int it = 0; it < 10; ++it){
        hipMemsetAsync(ap, 0, vb, stream);
        for (int cg0 = 0; cg0 < C_; cg0 += ncga){
            const int ncg = (C_ - cg0 < ncga) ? (C_ - cg0) : ncga;
            const int ng = (ncg + CPB - 1) / CPB;
            k_fwd  <<<TILES * ncg * B_, 512, 0, stream>>>(ph, csh, g, cg0, ncg, ncga);
            k_plane<<<NP    * ncg * B_, 512, 0, stream>>>(g, wh, pm3, ncg, ncga);
            k_inv  <<<TILES * ng  * B_, 512, 0, stream>>>(g, csh, ph, (float*)ap, sc, cg0, ncg, ng, ncga, it);
        }
        k_update<<<(B_ * NVOX) / 256, 256, 0, stream>>>(x, r, p, ap, lam1, sc, it);
        k_pupd  <<<(B_ * NVOX) / 256, 256, 0, stream>>>(p, ph, r, sc, it);
    }
}

// Round 8
// 6301.641 us; speedup vs baseline: 1.1191x; 1.1191x over previous
//
#include <hip/hip_runtime.h>
#include <hip/hip_fp16.h>

typedef float2 cplx;
typedef __half2 gpak;   // packed complex fp16 (re, im)

constexpr int B_   = 2;
constexpr int C_   = 12;
constexpr int NR   = 96;
constexpr int NC_  = 96;
constexpr int NS   = 48;
constexpr int NP   = 288;
constexpr int NCOL = NC_ * NS;      // 4608
constexpr int NVOX = NR * NCOL;     // 442368
constexpr int TILE = 64;            // cols per k_fwd/k_inv block (256-B bursts)
constexpr int TILES = NCOL / TILE;  // 72
constexpr int LSTR = 49;            // padded nc stride in k_plane LDS
constexpr int CPB  = 6;             // coils per k_inv block -> 2 ap slices, no atomics
constexpr int NSL  = 2;             // ap slices
constexpr float PI2 = 6.28318530717958647692f;
constexpr float R96 = 1.f/96.f, R48 = 1.f/48.f, R288 = 1.f/288.f;

// scalar slot map (floats, sc = 512 B)
#define RTR(it) (8 + 2*(it))
#define PAP(it) (32 + 2*(it))
#define PN(it)  (52 + 2*(it))

__device__ inline cplx cmulc(cplx a, cplx b){ return make_float2(a.x*b.x - a.y*b.y, a.x*b.y + a.y*b.x); }
__device__ inline cplx cmuljc(cplx a, cplx b){ return make_float2(a.x*b.x + a.y*b.y, a.y*b.x - a.x*b.y); }
__device__ inline cplx caddc(cplx a, cplx b){ return make_float2(a.x+b.x, a.y+b.y); }
__device__ inline cplx csubc(cplx a, cplx b){ return make_float2(a.x-b.x, a.y-b.y); }

__device__ __forceinline__ gpak pack_g(cplx v){ return __float22half2_rn(v); }
__device__ __forceinline__ cplx unpack_g(gpak h){ return __half22float2(h); }

__device__ inline void atomAddF(float* p, float v){
    __hip_atomic_fetch_add(p, v, __ATOMIC_RELAXED, __HIP_MEMORY_SCOPE_AGENT);
}

__device__ __forceinline__ cplx twf(float k, float rN){
    float s, c; __sincosf(-PI2 * k * rN, &s, &c);
    return make_float2(c, s);
}

// ---------------- register DFT cores ----------------
template<bool INV>
__device__ __forceinline__ cplx w16k(int k){
    constexpr float re[10] = {1.f, 0.92387953251f, 0.70710678119f, 0.38268343236f, 0.f,
                              -0.38268343236f, -0.70710678119f, -0.92387953251f, -1.f, -0.92387953251f};
    constexpr float im[10] = {0.f, -0.38268343236f, -0.70710678119f, -0.92387953251f, -1.f,
                              -0.92387953251f, -0.70710678119f, -0.38268343236f, 0.f, 0.38268343236f};
    return make_float2(re[k], INV ? -im[k] : im[k]);
}
template<bool INV>
__device__ __forceinline__ cplx w6k(int k){
    const float rr = (k == 1) ? 0.5f : -0.5f;
    const float ii = INV ? 0.86602540378f : -0.86602540378f;
    return make_float2(rr, ii);
}
template<bool INV>
__device__ __forceinline__ void r4(cplx& a0, cplx& a1, cplx& a2, cplx& a3){
    cplx t0 = caddc(a0, a2), t1 = csubc(a0, a2);
    cplx t2 = caddc(a1, a3), t3 = csubc(a1, a3);
    cplx it3 = INV ? make_float2(-t3.y, t3.x) : make_float2(t3.y, -t3.x);
    a0 = caddc(t0, t2); a1 = caddc(t1, it3);
    a2 = csubc(t0, t2); a3 = csubc(t1, it3);
}
template<bool INV>
__device__ __forceinline__ void r3(cplx& a0, cplx& a1, cplx& a2){
    cplx t1 = caddc(a1, a2), t2 = csubc(a1, a2);
    cplx m1 = make_float2(a0.x - 0.5f * t1.x, a0.y - 0.5f * t1.y);
    const float s3 = INV ? -0.8660254037844386f : 0.8660254037844386f;
    cplx b1 = make_float2(m1.x + s3 * t2.y, m1.y - s3 * t2.x);
    cplx b2 = make_float2(m1.x - s3 * t2.y, m1.y + s3 * t2.x);
    a0 = caddc(a0, t1); a1 = b1; a2 = b2;
}
template<bool INV>
__device__ __forceinline__ void dft16(cplx x[16]){
    cplx y[16];
    #pragma unroll
    for (int j = 0; j < 4; ++j){
        cplx a0 = x[j], a1 = x[j+4], a2 = x[j+8], a3 = x[j+12];
        r4<INV>(a0, a1, a2, a3);
        y[4*j+0] = a0;
        y[4*j+1] = (j == 0) ? a1 : cmulc(a1, w16k<INV>(j));
        y[4*j+2] = (j == 0) ? a2 : cmulc(a2, w16k<INV>(2*j));
        y[4*j+3] = (j == 0) ? a3 : cmulc(a3, w16k<INV>(3*j));
    }
    #pragma unroll
    for (int q = 0; q < 4; ++q){
        cplx a0 = y[q], a1 = y[q+4], a2 = y[q+8], a3 = y[q+12];
        r4<INV>(a0, a1, a2, a3);
        x[q] = a0; x[q+4] = a1; x[q+8] = a2; x[q+12] = a3;
    }
}
template<bool INV>
__device__ __forceinline__ void dft6(cplx x[6]){
    cplx y[6];
    { cplx a0 = x[0], a1 = x[2], a2 = x[4]; r3<INV>(a0, a1, a2); y[0] = a0; y[1] = a1; y[2] = a2; }
    { cplx a0 = x[1], a1 = x[3], a2 = x[5]; r3<INV>(a0, a1, a2);
      y[3] = a0; y[4] = cmulc(a1, w6k<INV>(1)); y[5] = cmulc(a2, w6k<INV>(2)); }
    #pragma unroll
    for (int q = 0; q < 3; ++q){
        cplx s = caddc(y[q], y[q+3]), d = csubc(y[q], y[q+3]);
        x[q] = s; x[q+3] = d;
    }
}

template<int NW>
__device__ inline float block_reduce(float v){
    #pragma unroll
    for (int o = 32; o >= 1; o >>= 1) v += __shfl_down(v, o, 64);
    __shared__ float sh[NW];
    const int lane = threadIdx.x & 63, wv = threadIdx.x >> 6;
    if (lane == 0) sh[wv] = v;
    __syncthreads();
    float s = 0.f;
    if (threadIdx.x == 0){
        #pragma unroll
        for (int w = 0; w < NW; ++w) s += sh[w];
    }
    return s;
}

// ---------------------------------------------------------------------------
// K1: coil = csh*ph (fp16 in), padded row FFT 96->288 via DIF 6x16.
// Products register-cached across the 3 a-slices; 256-B aligned g bursts.
// ---------------------------------------------------------------------------
__global__ __launch_bounds__(512, 4)
void k_fwd(const gpak* __restrict__ ph, const gpak* __restrict__ csh,
           gpak* __restrict__ g, int cg0, int ncg, int ncga)
{
    __shared__ cplx A[NR * TILE];
    const int tid = threadIdx.x, bid = blockIdx.x;
    const int tile = bid % TILES;
    const int rem = bid / TILES;
    const int gc = rem % ncg, b = rem / ncg, c = cg0 + gc;
    const int colbase = tile * TILE;
    const gpak* pp = ph  + (size_t)b * NVOX;
    const gpak* cs = csh + ((size_t)b * C_ + c) * NVOX;
    gpak* gg = g + (size_t)(b * ncga + gc) * ((size_t)NP * NCOL);

    cplx xr[2][6];
    #pragma unroll
    for (int it = 0; it < 2; ++it){
        const int id = tid + it * 512;
        const int m = id >> 6, col = id & 63;
        #pragma unroll
        for (int v = 0; v < 6; ++v){
            const int gi = (m + 16*v) * NCOL + colbase + col;
            xr[it][v] = cmulc(unpack_g(pp[gi]), unpack_g(cs[gi]));
        }
    }

    for (int a = 0; a < 3; ++a){
        if (a) __syncthreads();
        #pragma unroll
        for (int it = 0; it < 2; ++it){
            const int id = tid + it * 512;
            const int m = id >> 6, col = id & 63;
            cplx xv[6];
            if (a){
                cplx t = twf((float)(a*m), R288);
                const cplx stp = twf((float)(16*a), R288);
                #pragma unroll
                for (int v = 0; v < 6; ++v){ xv[v] = cmulc(xr[it][v], t); t = cmulc(t, stp); }
            } else {
                #pragma unroll
                for (int v = 0; v < 6; ++v) xv[v] = xr[it][v];
            }
            dft6<false>(xv);
            cplx* dst = &A[m * TILE + col];
            dst[0] = xv[0];
            const cplx w1 = twf((float)m, R96);
            cplx t = w1;
            #pragma unroll
            for (int r = 1; r < 6; ++r){ dst[16*r*TILE] = cmulc(xv[r], t); t = cmulc(t, w1); }
        }
        __syncthreads();
        if (tid < 384){
            const int r = tid >> 6, col = tid & 63;
            cplx d[16];
            #pragma unroll
            for (int m = 0; m < 16; ++m) d[m] = A[(m + 16*r) * TILE + col];
            dft16<false>(d);
            const cplx pref = twf((float)(32*a), R96);   // e^{-2pi i a/3}
            #pragma unroll
            for (int t = 0; t < 16; ++t)
                gg[(size_t)(18*t + 3*r + a) * NCOL + colbase + col] = pack_g(cmulc(d[t], pref));
        }
    }
}

// ---------------------------------------------------------------------------
// K2: per padded row: g <- conj(w) * IFFT2( pm * FFT2( w*g ) ), DIF->DIT,
// permuted fp16 mask, in-place passes, turnaround fused in registers.
// ---------------------------------------------------------------------------
__global__ __launch_bounds__(512, 4)
void k_plane(gpak* __restrict__ g, const gpak* __restrict__ wh,
             const __half* __restrict__ pmh, int ncg, int ncga)
{
    __shared__ cplx A[NC_ * LSTR];
    const int tid = threadIdx.x, bid = blockIdx.x;
    const int rp = bid % NP;
    const int rem = bid / NP;
    const int gc = rem % ncg, b = rem / ncg;
    gpak* gg = g + ((size_t)(b * ncga + gc) * NP + rp) * NCOL;
    const gpak*  wp  = wh  + ((size_t)b * NP + rp) * NCOL;
    const __half* pmv = pmh + ((size_t)b * NP + rp) * NCOL;

    // ph1: ns DIF p1 (radix-3) from global, x w
    #pragma unroll
    for (int it = 0; it < 3; ++it){
        const int id = tid + it * 512;
        const int m = id & 15, nc = id >> 4;
        cplx xv[3];
        #pragma unroll
        for (int v = 0; v < 3; ++v){
            const int e = nc * NS + m + 16*v;
            xv[v] = cmulc(unpack_g(gg[e]), unpack_g(wp[e]));
        }
        r3<false>(xv[0], xv[1], xv[2]);
        cplx* dst = &A[nc * LSTR + m];
        const cplx w1 = twf((float)m, R48);
        dst[0]  = xv[0];
        dst[16] = cmulc(xv[1], w1);
        dst[32] = cmulc(xv[2], cmulc(w1, w1));
    }
    __syncthreads();
    // ph2: ns DIF p2 (radix-16, contiguous, in place)
    if (tid < 288){
        const int rho = tid / 96, nc = tid - rho * 96;
        cplx* pA = &A[nc * LSTR + 16 * rho];
        cplx d[16];
        #pragma unroll
        for (int m = 0; m < 16; ++m) d[m] = pA[m];
        dft16<false>(d);
        #pragma unroll
        for (int t = 0; t < 16; ++t) pA[t] = d[t];
    }
    __syncthreads();
    // ph3: nc DIF p1 (radix-6, in place)
    #pragma unroll
    for (int it = 0; it < 2; ++it){
        const int id = tid + it * 512;
        if (id < 768){
            const int m = id / NS, ns = id - m * NS;
            cplx xv[6];
            #pragma unroll
            for (int v = 0; v < 6; ++v) xv[v] = A[(m + 16*v) * LSTR + ns];
            dft6<false>(xv);
            const cplx w1 = twf((float)m, R96);
            A[m * LSTR + ns] = xv[0];
            cplx t = w1;
            #pragma unroll
            for (int r = 1; r < 6; ++r){ A[(m + 16*r) * LSTR + ns] = cmulc(xv[r], t); t = cmulc(t, w1); }
        }
    }
    __syncthreads();
    // ph4: nc DIF p2 + permuted mask + nc DIT p2 — in registers
    if (tid < 288){
        const int r = tid / NS, ns = tid - r * NS;
        cplx d[16];
        #pragma unroll
        for (int m = 0; m < 16; ++m) d[m] = A[(m + 16*r) * LSTR + ns];
        dft16<false>(d);
        #pragma unroll
        for (int t = 0; t < 16; ++t){
            const float mval = __half2float(pmv[(6*t + r) * NS + ns]);
            d[t].x *= mval; d[t].y *= mval;
        }
        dft16<true>(d);
        #pragma unroll
        for (int m = 0; m < 16; ++m) A[(m + 16*r) * LSTR + ns] = d[m];
    }
    __syncthreads();
    // ph5: nc DIT p1 (undo radix-6, in place)
    #pragma unroll
    for (int it = 0; it < 2; ++it){
        const int id = tid + it * 512;
        if (id < 768){
            const int m = id / NS, ns = id - m * NS;
            cplx xv[6];
            const cplx w1 = twf(-(float)m, R96);
            cplx t = make_float2(1.f, 0.f);
            #pragma unroll
            for (int r = 0; r < 6; ++r){ xv[r] = cmulc(A[(m + 16*r) * LSTR + ns], t); t = cmulc(t, w1); }
            dft6<true>(xv);
            #pragma unroll
            for (int v = 0; v < 6; ++v) A[(m + 16*v) * LSTR + ns] = xv[v];
        }
    }
    __syncthreads();
    // ph6: ns DIT p2 (idft16 contiguous, in place)
    if (tid < 288){
        const int rho = tid / 96, nc = tid - rho * 96;
        cplx* pA = &A[nc * LSTR + 16 * rho];
        cplx d[16];
        #pragma unroll
        for (int t = 0; t < 16; ++t) d[t] = pA[t];
        dft16<true>(d);
        #pragma unroll
        for (int m = 0; m < 16; ++m) pA[m] = d[m];
    }
    __syncthreads();
    // ph7: ns DIT p1 (undo radix-3) x conj(w), store fp16
    #pragma unroll
    for (int it = 0; it < 3; ++it){
        const int id = tid + it * 512;
        const int m = id & 15, nc = id >> 4;
        const cplx w1 = twf(-(float)m, R48);
        cplx xv[3];
        xv[0] = A[nc * LSTR + m];
        xv[1] = cmulc(A[nc * LSTR + m + 16], w1);
        xv[2] = cmulc(A[nc * LSTR + m + 32], cmulc(w1, w1));
        r3<true>(xv[0], xv[1], xv[2]);
        #pragma unroll
        for (int v = 0; v < 3; ++v){
            const int e = nc * NS + m + 16*v;
            gg[e] = pack_g(cmuljc(xv[v], unpack_g(wp[e])));
        }
    }
}

// ---------------------------------------------------------------------------
// K3: row IFFT 288->96 (crop) via DIT 16x6 per a-slice, 6 coils per block;
// conj(csm) folded in; block OWNS its ap-slice tile -> plain stores, NO atomics.
// ---------------------------------------------------------------------------
__global__ __launch_bounds__(512, 3)
void k_inv(const gpak* __restrict__ g, const gpak* __restrict__ csh,
           const gpak* __restrict__ ph, cplx* __restrict__ ap,
           float* __restrict__ sc, int cg0, int ncg, int ng, int ncga, int iter)
{
    __shared__ cplx A[NR * TILE];
    const int tid = threadIdx.x, bid = blockIdx.x;
    const int tile = bid % TILES;
    const int rem = bid / TILES;
    const int gl = rem % ng, b = rem / ng;
    const int cbase = cg0 + gl * CPB;
    const int slice = cbase / CPB;      // 0 or 1
    const int colbase = tile * TILE;

    cplx accT[2][6];
    #pragma unroll
    for (int it = 0; it < 2; ++it)
        #pragma unroll
        for (int j = 0; j < 6; ++j) accT[it][j] = make_float2(0.f, 0.f);

    bool first = true;
    for (int ci = 0; ci < CPB; ++ci){
        const int c = cbase + ci;
        const gpak* gc_ = g + (size_t)(b * ncga + (c - cg0)) * ((size_t)NP * NCOL);
        const gpak* cs  = csh + ((size_t)b * C_ + c) * NVOX;

        for (int a = 0; a < 3; ++a){
            if (!first) __syncthreads();
            first = false;
            if (tid < 384){
                const int c6 = tid >> 6, col = tid & 63;
                cplx d[16];
                #pragma unroll
                for (int u = 0; u < 16; ++u)
                    d[u] = unpack_g(gc_[(size_t)(3*(c6 + 6*u) + a) * NCOL + colbase + col]);
                dft16<true>(d);
                #pragma unroll
                for (int q = 0; q < 16; ++q) A[(c6 + 6*q) * TILE + col] = d[q];
            }
            __syncthreads();
            #pragma unroll
            for (int it = 0; it < 2; ++it){
                const int id = tid + it * 512;
                const int q = id >> 6, col = id & 63;
                cplx xv[6];
                const cplx w1 = twf(-(float)q, R96);
                cplx t = make_float2(1.f, 0.f);
                #pragma unroll
                for (int cc = 0; cc < 6; ++cc){ xv[cc] = cmulc(A[(cc + 6*q) * TILE + col], t); t = cmulc(t, w1); }
                dft6<true>(xv);
                cplx f = twf(-(float)(a * (q + 96)), R288);
                f.x *= (1.f/288.f); f.y *= (1.f/288.f);
                const cplx fs = twf(-(float)(16 * a), R288);
                #pragma unroll
                for (int j = 0; j < 6; ++j){
                    const int gi = (q + 16*j) * NCOL + colbase + col;
                    accT[it][j] = caddc(accT[it][j], cmuljc(cmulc(xv[j], f), unpack_g(cs[gi])));
                    f = cmulc(f, fs);
                }
            }
        }
    }
    // epilogue: plain stores into owned ap-slice tile + local pAp partial
    cplx* aps = ap + ((size_t)slice * B_ + b) * NVOX;
    const gpak* pb = ph + (size_t)b * NVOX;
    float dotloc = 0.f;
    #pragma unroll
    for (int it = 0; it < 2; ++it){
        const int id = tid + it * 512;
        const int q = id >> 6, col = id & 63;
        #pragma unroll
        for (int j = 0; j < 6; ++j){
            const int gi = (q + 16*j) * NCOL + colbase + col;
            aps[gi] = accT[it][j];
            const cplx pv = unpack_g(pb[gi]);
            dotloc += pv.x * accT[it][j].x + pv.y * accT[it][j].y;
        }
    }
    const float s = block_reduce<8>(dotloc);
    if (tid == 0) atomAddF(&sc[PAP(iter) + b], s);
}

// ---------------------------------------------------------------------------
// prep kernels (once per solve)
// ---------------------------------------------------------------------------
__global__ __launch_bounds__(512)
void k_prep_csm(const cplx* __restrict__ csm, gpak* __restrict__ csh, int n)
{
    for (int i = blockIdx.x * 512 + threadIdx.x; i < n; i += gridDim.x * 512)
        csh[i] = pack_g(csm[i]);
}

__global__ __launch_bounds__(512)
void k_prep_wm(const cplx* __restrict__ wpsf, const float* __restrict__ mask,
               gpak* __restrict__ wh, __half* __restrict__ pmh)
{
    const int bid = blockIdx.x;            // b*NP + rp
    const cplx*  wsrc = wpsf + (size_t)bid * NCOL;
    const float* mk   = mask + (size_t)bid * NCOL;
    gpak*   wdst = wh  + (size_t)bid * NCOL;
    __half* out  = pmh + (size_t)bid * NCOL;
    for (int e = threadIdx.x; e < NCOL; e += 512){
        wdst[e] = pack_g(wsrc[e]);
        const int knc = e / NS, pns = e - knc * NS;
        const int kns = 3 * (pns & 15) + (pns >> 4);
        out[e] = __float2half(mk[knc * NS + kns] * (1.f / 4608.f));
    }
}

// ---------------------------------------------------------------------------
// CG kernels
// ---------------------------------------------------------------------------
__global__ __launch_bounds__(256)
void k_rr0(const cplx* __restrict__ r, gpak* __restrict__ ph, float* __restrict__ sc)
{
    const int i = blockIdx.x * 256 + threadIdx.x;
    const int b = i / NVOX;
    const cplx rv = r[i];
    ph[i] = pack_g(rv);
    const float s = block_reduce<4>(rv.x*rv.x + rv.y*rv.y);
    if (threadIdx.x == 0){ atomAddF(&sc[RTR(0) + b], s); atomAddF(&sc[PN(0) + b], s); }
}

__global__ __launch_bounds__(256)
void k_update(cplx* __restrict__ x, cplx* __restrict__ r,
              const cplx* __restrict__ p, const cplx* __restrict__ ap,
              const float* __restrict__ lam1, float* __restrict__ sc, int it)
{
    const int i = blockIdx.x * 256 + threadIdx.x;
    const int b = i / NVOX;
    const int iv = i - b * NVOX;
    const float rtr = sc[RTR(it) + b];
    const bool act = rtr > 1e-5f;
    const float lam = lam1[0];
    const float alpha = rtr / (sc[PAP(it) + b] + lam * sc[PN(it) + b]);
    const cplx pv = p[i];
    const cplx a0 = ap[(size_t)b * NVOX + iv];
    const cplx a1 = ap[((size_t)B_ + b) * NVOX + iv];
    cplx a = make_float2(a0.x + a1.x + lam * pv.x, a0.y + a1.y + lam * pv.y);
    cplx rv = r[i];
    if (act){
        cplx xv = x[i];
        xv.x += alpha * pv.x; xv.y += alpha * pv.y;
        x[i] = xv;
        rv.x -= alpha * a.x; rv.y -= alpha * a.y;
        r[i] = rv;
    }
    const float s = block_reduce<4>(rv.x*rv.x + rv.y*rv.y);
    if (threadIdx.x == 0) atomAddF(&sc[RTR(it+1) + b], s);
}

__global__ __launch_bounds__(256)
void k_pupd(cplx* __restrict__ p, gpak* __restrict__ ph,
            const cplx* __restrict__ r, float* __restrict__ sc, int it)
{
    const int i = blockIdx.x * 256 + threadIdx.x;
    const int b = i / NVOX;
    const float rtr = sc[RTR(it) + b];
    const bool act = rtr > 1e-5f;
    cplx pv = p[i];
    float loc;
    if (act){
        const float be = sc[RTR(it+1) + b] / rtr;
        const cplx rv = r[i];
        const cplx pn = make_float2(rv.x + be * pv.x, rv.y + be * pv.y);
        p[i] = pn; ph[i] = pack_g(pn);
        loc = pn.x*pn.x + pn.y*pn.y;
    } else {
        loc = pv.x*pv.x + pv.y*pv.y;
    }
    const float s = block_reduce<4>(loc);
    if (threadIdx.x == 0) atomAddF(&sc[PN(it+1) + b], s);
}

// ---------------------------------------------------------------------------
extern "C" void kernel_launch(void* const* d_in, const int* in_sizes, int n_in,
                              void* d_out, int out_size, void* d_ws, size_t ws_size,
                              hipStream_t stream)
{
    const cplx*  rhs  = (const cplx*)d_in[0];
    const cplx*  csm  = (const cplx*)d_in[1];
    const float* mask = (const float*)d_in[2];
    const cplx*  wpsf = (const cplx*)d_in[3];
    const float* lam1 = (const float*)d_in[4];

    const size_t vb   = (size_t)B_ * NVOX * sizeof(cplx);           // 7,077,888 B
    const size_t hv   = (size_t)B_ * NVOX * sizeof(gpak);           // 3.5 MB
    const size_t pmb  = (size_t)B_ * NP * NCOL * sizeof(__half);    // 5.3 MB
    const size_t whb  = (size_t)B_ * NP * NCOL * sizeof(gpak);      // 10.6 MB
    const size_t cshb = (size_t)B_ * C_ * NVOX * sizeof(gpak);      // 42.5 MB
    const size_t percoil = (size_t)B_ * NP * NCOL * sizeof(gpak);   // 10.6 MB

    char* ws = (char*)d_ws;
    float* sc = (float*)ws;
    size_t off = 512;
    cplx* r    = (cplx*)(ws + off); off += vb;
    cplx* p    = (cplx*)(ws + off); off += vb;
    gpak* ph   = (gpak*)(ws + off); off += hv;
    __half* pmh = (__half*)(ws + off); off += pmb;
    cplx* ap   = (cplx*)(ws + off); off += (size_t)NSL * vb;
    gpak* csh  = (gpak*)(ws + off); off += cshb;
    gpak* wh   = (gpak*)(ws + off); off += whb;
    gpak* g    = (gpak*)(ws + off);
    cplx* x    = (cplx*)d_out;

    int ncga = CPB;
    if (ws_size > off){
        size_t fit = (ws_size - off) / percoil;
        ncga = fit > (size_t)C_ ? C_ : (int)fit;
        ncga -= ncga % CPB;
        if (ncga < CPB) ncga = CPB;
    }

    hipMemsetAsync(d_out, 0, vb, stream);
    hipMemsetAsync(sc, 0, 512, stream);
    hipMemcpyAsync(r, rhs, vb, hipMemcpyDeviceToDevice, stream);
    hipMemcpyAsync(p, rhs, vb, hipMemcpyDeviceToDevice, stream);
    k_prep_csm<<<(B_ * C_ * NVOX) / 512, 512, 0, stream>>>(csm, csh, B_ * C_ * NVOX);
    k_prep_wm<<<B_ * NP, 512, 0, stream>>>(wpsf, mask, wh, pmh);
    k_rr0<<<(B_ * NVOX) / 256, 256, 0, stream>>>(r, ph, sc);

    for (int it = 0; it < 10; ++it){
        for (int cg0 = 0; cg0 < C_; cg0 += ncga){
            const int ncg = (C_ - cg0 < ncga) ? (C_ - cg0) : ncga;
            const int ng = ncg / CPB;
            k_fwd  <<<TILES * ncg * B_, 512, 0, stream>>>(ph, csh, g, cg0, ncg, ncga);
            k_plane<<<NP    * ncg * B_, 512, 0, stream>>>(g, wh, pmh, ncg, ncga);
            k_inv  <<<TILES * ng  * B_, 512, 0, stream>>>(g, csh, ph, ap, sc, cg0, ncg, ng, ncga, it);
        }
        k_update<<<(B_ * NVOX) / 256, 256, 0, stream>>>(x, r, p, ap, lam1, sc, it);
        k_pupd  <<<(B_ * NVOX) / 256, 256, 0, stream>>>(p, ph, r, sc, it);
    }
}

// Round 9
// 6007.379 us; speedup vs baseline: 1.1739x; 1.0490x over previous
//
#include <hip/hip_runtime.h>
#include <hip/hip_fp16.h>

typedef float2 cplx;
typedef __half2 gpak;   // packed complex fp16 (re, im)

constexpr int B_   = 2;
constexpr int C_   = 12;
constexpr int NR   = 96;
constexpr int NC_  = 96;
constexpr int NS   = 48;
constexpr int NP   = 288;
constexpr int NCOL = NC_ * NS;      // 4608
constexpr int NVOX = NR * NCOL;     // 442368
constexpr int TILE = 64;            // cols per k_fwd/k_inv block (256-B bursts)
constexpr int TILES = NCOL / TILE;  // 72
constexpr int LSTR = 49;            // padded nc stride in k_plane LDS
constexpr int CPB  = 2;             // coils per k_inv block -> 6 slices, grid 864
constexpr int NSL  = C_ / CPB;      // 6 ap slices
constexpr float PI2 = 6.28318530717958647692f;
constexpr float R96 = 1.f/96.f, R48 = 1.f/48.f, R288 = 1.f/288.f;

// scalar slot map (floats, sc = 512 B)
#define RTR(it) (8 + 2*(it))
#define PAP(it) (32 + 2*(it))
#define PN(it)  (52 + 2*(it))

__device__ inline cplx cmulc(cplx a, cplx b){ return make_float2(a.x*b.x - a.y*b.y, a.x*b.y + a.y*b.x); }
__device__ inline cplx cmuljc(cplx a, cplx b){ return make_float2(a.x*b.x + a.y*b.y, a.y*b.x - a.x*b.y); }
__device__ inline cplx caddc(cplx a, cplx b){ return make_float2(a.x+b.x, a.y+b.y); }
__device__ inline cplx csubc(cplx a, cplx b){ return make_float2(a.x-b.x, a.y-b.y); }

__device__ __forceinline__ gpak pack_g(cplx v){ return __float22half2_rn(v); }
__device__ __forceinline__ cplx unpack_g(gpak h){ return __half22float2(h); }

__device__ inline void atomAddF(float* p, float v){
    __hip_atomic_fetch_add(p, v, __ATOMIC_RELAXED, __HIP_MEMORY_SCOPE_AGENT);
}

__device__ __forceinline__ cplx twf(float k, float rN){
    float s, c; __sincosf(-PI2 * k * rN, &s, &c);
    return make_float2(c, s);
}

// ---------------- register DFT cores ----------------
template<bool INV>
__device__ __forceinline__ cplx w16k(int k){
    constexpr float re[10] = {1.f, 0.92387953251f, 0.70710678119f, 0.38268343236f, 0.f,
                              -0.38268343236f, -0.70710678119f, -0.92387953251f, -1.f, -0.92387953251f};
    constexpr float im[10] = {0.f, -0.38268343236f, -0.70710678119f, -0.92387953251f, -1.f,
                              -0.92387953251f, -0.70710678119f, -0.38268343236f, 0.f, 0.38268343236f};
    return make_float2(re[k], INV ? -im[k] : im[k]);
}
template<bool INV>
__device__ __forceinline__ cplx w6k(int k){
    const float rr = (k == 1) ? 0.5f : -0.5f;
    const float ii = INV ? 0.86602540378f : -0.86602540378f;
    return make_float2(rr, ii);
}
template<bool INV>
__device__ __forceinline__ void r4(cplx& a0, cplx& a1, cplx& a2, cplx& a3){
    cplx t0 = caddc(a0, a2), t1 = csubc(a0, a2);
    cplx t2 = caddc(a1, a3), t3 = csubc(a1, a3);
    cplx it3 = INV ? make_float2(-t3.y, t3.x) : make_float2(t3.y, -t3.x);
    a0 = caddc(t0, t2); a1 = caddc(t1, it3);
    a2 = csubc(t0, t2); a3 = csubc(t1, it3);
}
template<bool INV>
__device__ __forceinline__ void r3(cplx& a0, cplx& a1, cplx& a2){
    cplx t1 = caddc(a1, a2), t2 = csubc(a1, a2);
    cplx m1 = make_float2(a0.x - 0.5f * t1.x, a0.y - 0.5f * t1.y);
    const float s3 = INV ? -0.8660254037844386f : 0.8660254037844386f;
    cplx b1 = make_float2(m1.x + s3 * t2.y, m1.y - s3 * t2.x);
    cplx b2 = make_float2(m1.x - s3 * t2.y, m1.y + s3 * t2.x);
    a0 = caddc(a0, t1); a1 = b1; a2 = b2;
}
template<bool INV>
__device__ __forceinline__ void dft16(cplx x[16]){
    cplx y[16];
    #pragma unroll
    for (int j = 0; j < 4; ++j){
        cplx a0 = x[j], a1 = x[j+4], a2 = x[j+8], a3 = x[j+12];
        r4<INV>(a0, a1, a2, a3);
        y[4*j+0] = a0;
        y[4*j+1] = (j == 0) ? a1 : cmulc(a1, w16k<INV>(j));
        y[4*j+2] = (j == 0) ? a2 : cmulc(a2, w16k<INV>(2*j));
        y[4*j+3] = (j == 0) ? a3 : cmulc(a3, w16k<INV>(3*j));
    }
    #pragma unroll
    for (int q = 0; q < 4; ++q){
        cplx a0 = y[q], a1 = y[q+4], a2 = y[q+8], a3 = y[q+12];
        r4<INV>(a0, a1, a2, a3);
        x[q] = a0; x[q+4] = a1; x[q+8] = a2; x[q+12] = a3;
    }
}
template<bool INV>
__device__ __forceinline__ void dft6(cplx x[6]){
    cplx y[6];
    { cplx a0 = x[0], a1 = x[2], a2 = x[4]; r3<INV>(a0, a1, a2); y[0] = a0; y[1] = a1; y[2] = a2; }
    { cplx a0 = x[1], a1 = x[3], a2 = x[5]; r3<INV>(a0, a1, a2);
      y[3] = a0; y[4] = cmulc(a1, w6k<INV>(1)); y[5] = cmulc(a2, w6k<INV>(2)); }
    #pragma unroll
    for (int q = 0; q < 3; ++q){
        cplx s = caddc(y[q], y[q+3]), d = csubc(y[q], y[q+3]);
        x[q] = s; x[q+3] = d;
    }
}

template<int NW>
__device__ inline float block_reduce(float v){
    #pragma unroll
    for (int o = 32; o >= 1; o >>= 1) v += __shfl_down(v, o, 64);
    __shared__ float sh[NW];
    const int lane = threadIdx.x & 63, wv = threadIdx.x >> 6;
    if (lane == 0) sh[wv] = v;
    __syncthreads();
    float s = 0.f;
    if (threadIdx.x == 0){
        #pragma unroll
        for (int w = 0; w < NW; ++w) s += sh[w];
    }
    return s;
}

// ---------------------------------------------------------------------------
// K1: coil = csh*ph (fp16 in), padded row FFT 96->288 via DIF 6x16.
// Products register-cached across the 3 a-slices; 256-B aligned g bursts.
// ---------------------------------------------------------------------------
__global__ __launch_bounds__(512, 4)
void k_fwd(const gpak* __restrict__ ph, const gpak* __restrict__ csh,
           gpak* __restrict__ g, int cg0, int ncg, int ncga)
{
    __shared__ cplx A[NR * TILE];
    const int tid = threadIdx.x, bid = blockIdx.x;
    const int tile = bid % TILES;
    const int rem = bid / TILES;
    const int gc = rem % ncg, b = rem / ncg, c = cg0 + gc;
    const int colbase = tile * TILE;
    const gpak* pp = ph  + (size_t)b * NVOX;
    const gpak* cs = csh + ((size_t)b * C_ + c) * NVOX;
    gpak* gg = g + (size_t)(b * ncga + gc) * ((size_t)NP * NCOL);

    cplx xr[2][6];
    #pragma unroll
    for (int it = 0; it < 2; ++it){
        const int id = tid + it * 512;
        const int m = id >> 6, col = id & 63;
        #pragma unroll
        for (int v = 0; v < 6; ++v){
            const int gi = (m + 16*v) * NCOL + colbase + col;
            xr[it][v] = cmulc(unpack_g(pp[gi]), unpack_g(cs[gi]));
        }
    }

    for (int a = 0; a < 3; ++a){
        if (a) __syncthreads();
        #pragma unroll
        for (int it = 0; it < 2; ++it){
            const int id = tid + it * 512;
            const int m = id >> 6, col = id & 63;
            cplx xv[6];
            if (a){
                cplx t = twf((float)(a*m), R288);
                const cplx stp = twf((float)(16*a), R288);
                #pragma unroll
                for (int v = 0; v < 6; ++v){ xv[v] = cmulc(xr[it][v], t); t = cmulc(t, stp); }
            } else {
                #pragma unroll
                for (int v = 0; v < 6; ++v) xv[v] = xr[it][v];
            }
            dft6<false>(xv);
            cplx* dst = &A[m * TILE + col];
            dst[0] = xv[0];
            const cplx w1 = twf((float)m, R96);
            cplx t = w1;
            #pragma unroll
            for (int r = 1; r < 6; ++r){ dst[16*r*TILE] = cmulc(xv[r], t); t = cmulc(t, w1); }
        }
        __syncthreads();
        if (tid < 384){
            const int r = tid >> 6, col = tid & 63;
            cplx d[16];
            #pragma unroll
            for (int m = 0; m < 16; ++m) d[m] = A[(m + 16*r) * TILE + col];
            dft16<false>(d);
            const cplx pref = twf((float)(32*a), R96);   // e^{-2pi i a/3}
            #pragma unroll
            for (int t = 0; t < 16; ++t)
                gg[(size_t)(18*t + 3*r + a) * NCOL + colbase + col] = pack_g(cmulc(d[t], pref));
        }
    }
}

// ---------------------------------------------------------------------------
// K2: per padded row: g <- conj(w) * IFFT2( pm * FFT2( w*g ) ), DIF->DIT,
// permuted fp16 mask, in-place passes, turnaround fused in registers.
// ---------------------------------------------------------------------------
__global__ __launch_bounds__(512, 4)
void k_plane(gpak* __restrict__ g, const gpak* __restrict__ wh,
             const __half* __restrict__ pmh, int ncg, int ncga)
{
    __shared__ cplx A[NC_ * LSTR];
    const int tid = threadIdx.x, bid = blockIdx.x;
    const int rp = bid % NP;
    const int rem = bid / NP;
    const int gc = rem % ncg, b = rem / ncg;
    gpak* gg = g + ((size_t)(b * ncga + gc) * NP + rp) * NCOL;
    const gpak*  wp  = wh  + ((size_t)b * NP + rp) * NCOL;
    const __half* pmv = pmh + ((size_t)b * NP + rp) * NCOL;

    // ph1: ns DIF p1 (radix-3) from global, x w
    #pragma unroll
    for (int it = 0; it < 3; ++it){
        const int id = tid + it * 512;
        const int m = id & 15, nc = id >> 4;
        cplx xv[3];
        #pragma unroll
        for (int v = 0; v < 3; ++v){
            const int e = nc * NS + m + 16*v;
            xv[v] = cmulc(unpack_g(gg[e]), unpack_g(wp[e]));
        }
        r3<false>(xv[0], xv[1], xv[2]);
        cplx* dst = &A[nc * LSTR + m];
        const cplx w1 = twf((float)m, R48);
        dst[0]  = xv[0];
        dst[16] = cmulc(xv[1], w1);
        dst[32] = cmulc(xv[2], cmulc(w1, w1));
    }
    __syncthreads();
    // ph2: ns DIF p2 (radix-16, contiguous, in place)
    if (tid < 288){
        const int rho = tid / 96, nc = tid - rho * 96;
        cplx* pA = &A[nc * LSTR + 16 * rho];
        cplx d[16];
        #pragma unroll
        for (int m = 0; m < 16; ++m) d[m] = pA[m];
        dft16<false>(d);
        #pragma unroll
        for (int t = 0; t < 16; ++t) pA[t] = d[t];
    }
    __syncthreads();
    // ph3: nc DIF p1 (radix-6, in place)
    #pragma unroll
    for (int it = 0; it < 2; ++it){
        const int id = tid + it * 512;
        if (id < 768){
            const int m = id / NS, ns = id - m * NS;
            cplx xv[6];
            #pragma unroll
            for (int v = 0; v < 6; ++v) xv[v] = A[(m + 16*v) * LSTR + ns];
            dft6<false>(xv);
            const cplx w1 = twf((float)m, R96);
            A[m * LSTR + ns] = xv[0];
            cplx t = w1;
            #pragma unroll
            for (int r = 1; r < 6; ++r){ A[(m + 16*r) * LSTR + ns] = cmulc(xv[r], t); t = cmulc(t, w1); }
        }
    }
    __syncthreads();
    // ph4: nc DIF p2 + permuted mask + nc DIT p2 — in registers
    if (tid < 288){
        const int r = tid / NS, ns = tid - r * NS;
        cplx d[16];
        #pragma unroll
        for (int m = 0; m < 16; ++m) d[m] = A[(m + 16*r) * LSTR + ns];
        dft16<false>(d);
        #pragma unroll
        for (int t = 0; t < 16; ++t){
            const float mval = __half2float(pmv[(6*t + r) * NS + ns]);
            d[t].x *= mval; d[t].y *= mval;
        }
        dft16<true>(d);
        #pragma unroll
        for (int m = 0; m < 16; ++m) A[(m + 16*r) * LSTR + ns] = d[m];
    }
    __syncthreads();
    // ph5: nc DIT p1 (undo radix-6, in place)
    #pragma unroll
    for (int it = 0; it < 2; ++it){
        const int id = tid + it * 512;
        if (id < 768){
            const int m = id / NS, ns = id - m * NS;
            cplx xv[6];
            const cplx w1 = twf(-(float)m, R96);
            cplx t = make_float2(1.f, 0.f);
            #pragma unroll
            for (int r = 0; r < 6; ++r){ xv[r] = cmulc(A[(m + 16*r) * LSTR + ns], t); t = cmulc(t, w1); }
            dft6<true>(xv);
            #pragma unroll
            for (int v = 0; v < 6; ++v) A[(m + 16*v) * LSTR + ns] = xv[v];
        }
    }
    __syncthreads();
    // ph6: ns DIT p2 (idft16 contiguous, in place)
    if (tid < 288){
        const int rho = tid / 96, nc = tid - rho * 96;
        cplx* pA = &A[nc * LSTR + 16 * rho];
        cplx d[16];
        #pragma unroll
        for (int t = 0; t < 16; ++t) d[t] = pA[t];
        dft16<true>(d);
        #pragma unroll
        for (int m = 0; m < 16; ++m) pA[m] = d[m];
    }
    __syncthreads();
    // ph7: ns DIT p1 (undo radix-3) x conj(w), store fp16
    #pragma unroll
    for (int it = 0; it < 3; ++it){
        const int id = tid + it * 512;
        const int m = id & 15, nc = id >> 4;
        const cplx w1 = twf(-(float)m, R48);
        cplx xv[3];
        xv[0] = A[nc * LSTR + m];
        xv[1] = cmulc(A[nc * LSTR + m + 16], w1);
        xv[2] = cmulc(A[nc * LSTR + m + 32], cmulc(w1, w1));
        r3<true>(xv[0], xv[1], xv[2]);
        #pragma unroll
        for (int v = 0; v < 3; ++v){
            const int e = nc * NS + m + 16*v;
            gg[e] = pack_g(cmuljc(xv[v], unpack_g(wp[e])));
        }
    }
}

// ---------------------------------------------------------------------------
// K3: row IFFT 288->96 (crop) via DIT 16x6 per a-slice, 2 coils per block;
// conj(csm) folded in; block OWNS its ap-slice tile -> plain stores, NO atomics.
// ---------------------------------------------------------------------------
__global__ __launch_bounds__(512, 3)
void k_inv(const gpak* __restrict__ g, const gpak* __restrict__ csh,
           const gpak* __restrict__ ph, cplx* __restrict__ ap,
           float* __restrict__ sc, int cg0, int ncg, int ng, int ncga, int iter)
{
    __shared__ cplx A[NR * TILE];
    const int tid = threadIdx.x, bid = blockIdx.x;
    const int tile = bid % TILES;
    const int rem = bid / TILES;
    const int gl = rem % ng, b = rem / ng;
    const int cbase = cg0 + gl * CPB;
    const int slice = cbase / CPB;      // 0..5
    const int colbase = tile * TILE;

    cplx accT[2][6];
    #pragma unroll
    for (int it = 0; it < 2; ++it)
        #pragma unroll
        for (int j = 0; j < 6; ++j) accT[it][j] = make_float2(0.f, 0.f);

    bool first = true;
    for (int ci = 0; ci < CPB; ++ci){
        const int c = cbase + ci;
        const gpak* gc_ = g + (size_t)(b * ncga + (c - cg0)) * ((size_t)NP * NCOL);
        const gpak* cs  = csh + ((size_t)b * C_ + c) * NVOX;

        for (int a = 0; a < 3; ++a){
            if (!first) __syncthreads();
            first = false;
            if (tid < 384){
                const int c6 = tid >> 6, col = tid & 63;
                cplx d[16];
                #pragma unroll
                for (int u = 0; u < 16; ++u)
                    d[u] = unpack_g(gc_[(size_t)(3*(c6 + 6*u) + a) * NCOL + colbase + col]);
                dft16<true>(d);
                #pragma unroll
                for (int q = 0; q < 16; ++q) A[(c6 + 6*q) * TILE + col] = d[q];
            }
            __syncthreads();
            #pragma unroll
            for (int it = 0; it < 2; ++it){
                const int id = tid + it * 512;
                const int q = id >> 6, col = id & 63;
                cplx xv[6];
                const cplx w1 = twf(-(float)q, R96);
                cplx t = make_float2(1.f, 0.f);
                #pragma unroll
                for (int cc = 0; cc < 6; ++cc){ xv[cc] = cmulc(A[(cc + 6*q) * TILE + col], t); t = cmulc(t, w1); }
                dft6<true>(xv);
                cplx f = twf(-(float)(a * (q + 96)), R288);
                f.x *= (1.f/288.f); f.y *= (1.f/288.f);
                const cplx fs = twf(-(float)(16 * a), R288);
                #pragma unroll
                for (int j = 0; j < 6; ++j){
                    const int gi = (q + 16*j) * NCOL + colbase + col;
                    accT[it][j] = caddc(accT[it][j], cmuljc(cmulc(xv[j], f), unpack_g(cs[gi])));
                    f = cmulc(f, fs);
                }
            }
        }
    }
    // epilogue: plain stores into owned ap-slice tile + local pAp partial
    cplx* aps = ap + ((size_t)slice * B_ + b) * NVOX;
    const gpak* pb = ph + (size_t)b * NVOX;
    float dotloc = 0.f;
    #pragma unroll
    for (int it = 0; it < 2; ++it){
        const int id = tid + it * 512;
        const int q = id >> 6, col = id & 63;
        #pragma unroll
        for (int j = 0; j < 6; ++j){
            const int gi = (q + 16*j) * NCOL + colbase + col;
            aps[gi] = accT[it][j];
            const cplx pv = unpack_g(pb[gi]);
            dotloc += pv.x * accT[it][j].x + pv.y * accT[it][j].y;
        }
    }
    const float s = block_reduce<8>(dotloc);
    if (tid == 0) atomAddF(&sc[PAP(iter) + b], s);
}

// ---------------------------------------------------------------------------
// prep kernels (once per solve)
// ---------------------------------------------------------------------------
__global__ __launch_bounds__(512)
void k_prep_csm(const cplx* __restrict__ csm, gpak* __restrict__ csh, int n)
{
    for (int i = blockIdx.x * 512 + threadIdx.x; i < n; i += gridDim.x * 512)
        csh[i] = pack_g(csm[i]);
}

__global__ __launch_bounds__(512)
void k_prep_wm(const cplx* __restrict__ wpsf, const float* __restrict__ mask,
               gpak* __restrict__ wh, __half* __restrict__ pmh)
{
    const int bid = blockIdx.x;            // b*NP + rp
    const cplx*  wsrc = wpsf + (size_t)bid * NCOL;
    const float* mk   = mask + (size_t)bid * NCOL;
    gpak*   wdst = wh  + (size_t)bid * NCOL;
    __half* out  = pmh + (size_t)bid * NCOL;
    for (int e = threadIdx.x; e < NCOL; e += 512){
        wdst[e] = pack_g(wsrc[e]);
        const int knc = e / NS, pns = e - knc * NS;
        const int kns = 3 * (pns & 15) + (pns >> 4);
        out[e] = __float2half(mk[knc * NS + kns] * (1.f / 4608.f));
    }
}

// ---------------------------------------------------------------------------
// CG kernels
// ---------------------------------------------------------------------------
__global__ __launch_bounds__(256)
void k_rr0(const cplx* __restrict__ r, gpak* __restrict__ ph, float* __restrict__ sc)
{
    const int i = blockIdx.x * 256 + threadIdx.x;
    const int b = i / NVOX;
    const cplx rv = r[i];
    ph[i] = pack_g(rv);
    const float s = block_reduce<4>(rv.x*rv.x + rv.y*rv.y);
    if (threadIdx.x == 0){ atomAddF(&sc[RTR(0) + b], s); atomAddF(&sc[PN(0) + b], s); }
}

__global__ __launch_bounds__(256)
void k_update(cplx* __restrict__ x, cplx* __restrict__ r,
              const cplx* __restrict__ p, const cplx* __restrict__ ap,
              const float* __restrict__ lam1, float* __restrict__ sc, int it)
{
    const int i = blockIdx.x * 256 + threadIdx.x;
    const int b = i / NVOX;
    const int iv = i - b * NVOX;
    const float rtr = sc[RTR(it) + b];
    const bool act = rtr > 1e-5f;
    const float lam = lam1[0];
    const float alpha = rtr / (sc[PAP(it) + b] + lam * sc[PN(it) + b]);
    const cplx pv = p[i];
    cplx a = make_float2(lam * pv.x, lam * pv.y);
    #pragma unroll
    for (int gp = 0; gp < NSL; ++gp){
        const cplx t = ap[((size_t)gp * B_ + b) * NVOX + iv];
        a.x += t.x; a.y += t.y;
    }
    cplx rv = r[i];
    if (act){
        cplx xv = x[i];
        xv.x += alpha * pv.x; xv.y += alpha * pv.y;
        x[i] = xv;
        rv.x -= alpha * a.x; rv.y -= alpha * a.y;
        r[i] = rv;
    }
    const float s = block_reduce<4>(rv.x*rv.x + rv.y*rv.y);
    if (threadIdx.x == 0) atomAddF(&sc[RTR(it+1) + b], s);
}

__global__ __launch_bounds__(256)
void k_pupd(cplx* __restrict__ p, gpak* __restrict__ ph,
            const cplx* __restrict__ r, float* __restrict__ sc, int it)
{
    const int i = blockIdx.x * 256 + threadIdx.x;
    const int b = i / NVOX;
    const float rtr = sc[RTR(it) + b];
    const bool act = rtr > 1e-5f;
    cplx pv = p[i];
    float loc;
    if (act){
        const float be = sc[RTR(it+1) + b] / rtr;
        const cplx rv = r[i];
        const cplx pn = make_float2(rv.x + be * pv.x, rv.y + be * pv.y);
        p[i] = pn; ph[i] = pack_g(pn);
        loc = pn.x*pn.x + pn.y*pn.y;
    } else {
        loc = pv.x*pv.x + pv.y*pv.y;
    }
    const float s = block_reduce<4>(loc);
    if (threadIdx.x == 0) atomAddF(&sc[PN(it+1) + b], s);
}

// ---------------------------------------------------------------------------
extern "C" void kernel_launch(void* const* d_in, const int* in_sizes, int n_in,
                              void* d_out, int out_size, void* d_ws, size_t ws_size,
                              hipStream_t stream)
{
    const cplx*  rhs  = (const cplx*)d_in[0];
    const cplx*  csm  = (const cplx*)d_in[1];
    const float* mask = (const float*)d_in[2];
    const cplx*  wpsf = (const cplx*)d_in[3];
    const float* lam1 = (const float*)d_in[4];

    const size_t vb   = (size_t)B_ * NVOX * sizeof(cplx);           // 7,077,888 B
    const size_t hv   = (size_t)B_ * NVOX * sizeof(gpak);           // 3.5 MB
    const size_t pmb  = (size_t)B_ * NP * NCOL * sizeof(__half);    // 5.3 MB
    const size_t whb  = (size_t)B_ * NP * NCOL * sizeof(gpak);      // 10.6 MB
    const size_t cshb = (size_t)B_ * C_ * NVOX * sizeof(gpak);      // 42.5 MB
    const size_t percoil = (size_t)B_ * NP * NCOL * sizeof(gpak);   // 10.6 MB

    char* ws = (char*)d_ws;
    float* sc = (float*)ws;
    size_t off = 512;
    cplx* r    = (cplx*)(ws + off); off += vb;
    cplx* p    = (cplx*)(ws + off); off += vb;
    gpak* ph   = (gpak*)(ws + off); off += hv;
    __half* pmh = (__half*)(ws + off); off += pmb;
    cplx* ap   = (cplx*)(ws + off); off += (size_t)NSL * vb;
    gpak* csh  = (gpak*)(ws + off); off += cshb;
    gpak* wh   = (gpak*)(ws + off); off += whb;
    gpak* g    = (gpak*)(ws + off);
    cplx* x    = (cplx*)d_out;

    int ncga = CPB;
    if (ws_size > off){
        size_t fit = (ws_size - off) / percoil;
        ncga = fit > (size_t)C_ ? C_ : (int)fit;
        ncga -= ncga % CPB;
        if (ncga < CPB) ncga = CPB;
    }

    hipMemsetAsync(d_out, 0, vb, stream);
    hipMemsetAsync(sc, 0, 512, stream);
    hipMemcpyAsync(r, rhs, vb, hipMemcpyDeviceToDevice, stream);
    hipMemcpyAsync(p, rhs, vb, hipMemcpyDeviceToDevice, stream);
    k_prep_csm<<<(B_ * C_ * NVOX) / 512, 512, 0, stream>>>(csm, csh, B_ * C_ * NVOX);
    k_prep_wm<<<B_ * NP, 512, 0, stream>>>(wpsf, mask, wh, pmh);
    k_rr0<<<(B_ * NVOX) / 256, 256, 0, stream>>>(r, ph, sc);

    for (int it = 0; it < 10; ++it){
        for (int cg0 = 0; cg0 < C_; cg0 += ncga){
            const int ncg = (C_ - cg0 < ncga) ? (C_ - cg0) : ncga;
            const int ng = ncg / CPB;
            k_fwd  <<<TILES * ncg * B_, 512, 0, stream>>>(ph, csh, g, cg0, ncg, ncga);
            k_plane<<<NP    * ncg * B_, 512, 0, stream>>>(g, wh, pmh, ncg, ncga);
            k_inv  <<<TILES * ng  * B_, 512, 0, stream>>>(g, csh, ph, ap, sc, cg0, ncg, ng, ncga, it);
        }
        k_update<<<(B_ * NVOX) / 256, 256, 0, stream>>>(x, r, p, ap, lam1, sc, it);
        k_pupd  <<<(B_ * NVOX) / 256, 256, 0, stream>>>(p, ph, r, sc, it);
    }
}

// Round 10
// 5903.127 us; speedup vs baseline: 1.1947x; 1.0177x over previous
//
#include <hip/hip_runtime.h>
#include <hip/hip_fp16.h>

typedef float2 cplx;
typedef __half2 gpak;   // packed complex fp16 (re, im)

constexpr int B_   = 2;
constexpr int C_   = 12;
constexpr int NR   = 96;
constexpr int NC_  = 96;
constexpr int NS   = 48;
constexpr int NP   = 288;
constexpr int NCOL = NC_ * NS;      // 4608
constexpr int NVOX = NR * NCOL;     // 442368
constexpr int TILE = 64;            // cols per k_fwd/k_inv block (256-B bursts)
constexpr int TILES = NCOL / TILE;  // 72
constexpr int LSTR = 49;            // padded nc stride in k_plane LDS
constexpr int CPB  = 2;             // coils per k_inv block
constexpr int NSL  = C_ / CPB;      // 6 ap slices
constexpr int NCGA_MAX = 6;         // coils per chain -> chain working set ~157 MB, LLC-resident
constexpr float PI2 = 6.28318530717958647692f;
constexpr float R96 = 1.f/96.f, R48 = 1.f/48.f, R288 = 1.f/288.f;

// scalar slot map (floats, sc = 512 B)
#define RTR(it) (8 + 2*(it))
#define PAP(it) (32 + 2*(it))
#define PN(it)  (52 + 2*(it))

__device__ inline cplx cmulc(cplx a, cplx b){ return make_float2(a.x*b.x - a.y*b.y, a.x*b.y + a.y*b.x); }
__device__ inline cplx cmuljc(cplx a, cplx b){ return make_float2(a.x*b.x + a.y*b.y, a.y*b.x - a.x*b.y); }
__device__ inline cplx caddc(cplx a, cplx b){ return make_float2(a.x+b.x, a.y+b.y); }
__device__ inline cplx csubc(cplx a, cplx b){ return make_float2(a.x-b.x, a.y-b.y); }

__device__ __forceinline__ gpak pack_g(cplx v){ return __float22half2_rn(v); }
__device__ __forceinline__ cplx unpack_g(gpak h){ return __half22float2(h); }

__device__ inline void atomAddF(float* p, float v){
    __hip_atomic_fetch_add(p, v, __ATOMIC_RELAXED, __HIP_MEMORY_SCOPE_AGENT);
}

__device__ __forceinline__ cplx twf(float k, float rN){
    float s, c; __sincosf(-PI2 * k * rN, &s, &c);
    return make_float2(c, s);
}

// ---------------- register DFT cores ----------------
template<bool INV>
__device__ __forceinline__ cplx w16k(int k){
    constexpr float re[10] = {1.f, 0.92387953251f, 0.70710678119f, 0.38268343236f, 0.f,
                              -0.38268343236f, -0.70710678119f, -0.92387953251f, -1.f, -0.92387953251f};
    constexpr float im[10] = {0.f, -0.38268343236f, -0.70710678119f, -0.92387953251f, -1.f,
                              -0.92387953251f, -0.70710678119f, -0.38268343236f, 0.f, 0.38268343236f};
    return make_float2(re[k], INV ? -im[k] : im[k]);
}
template<bool INV>
__device__ __forceinline__ cplx w6k(int k){
    const float rr = (k == 1) ? 0.5f : -0.5f;
    const float ii = INV ? 0.86602540378f : -0.86602540378f;
    return make_float2(rr, ii);
}
template<bool INV>
__device__ __forceinline__ void r4(cplx& a0, cplx& a1, cplx& a2, cplx& a3){
    cplx t0 = caddc(a0, a2), t1 = csubc(a0, a2);
    cplx t2 = caddc(a1, a3), t3 = csubc(a1, a3);
    cplx it3 = INV ? make_float2(-t3.y, t3.x) : make_float2(t3.y, -t3.x);
    a0 = caddc(t0, t2); a1 = caddc(t1, it3);
    a2 = csubc(t0, t2); a3 = csubc(t1, it3);
}
template<bool INV>
__device__ __forceinline__ void r3(cplx& a0, cplx& a1, cplx& a2){
    cplx t1 = caddc(a1, a2), t2 = csubc(a1, a2);
    cplx m1 = make_float2(a0.x - 0.5f * t1.x, a0.y - 0.5f * t1.y);
    const float s3 = INV ? -0.8660254037844386f : 0.8660254037844386f;
    cplx b1 = make_float2(m1.x + s3 * t2.y, m1.y - s3 * t2.x);
    cplx b2 = make_float2(m1.x - s3 * t2.y, m1.y + s3 * t2.x);
    a0 = caddc(a0, t1); a1 = b1; a2 = b2;
}
template<bool INV>
__device__ __forceinline__ void dft16(cplx x[16]){
    cplx y[16];
    #pragma unroll
    for (int j = 0; j < 4; ++j){
        cplx a0 = x[j], a1 = x[j+4], a2 = x[j+8], a3 = x[j+12];
        r4<INV>(a0, a1, a2, a3);
        y[4*j+0] = a0;
        y[4*j+1] = (j == 0) ? a1 : cmulc(a1, w16k<INV>(j));
        y[4*j+2] = (j == 0) ? a2 : cmulc(a2, w16k<INV>(2*j));
        y[4*j+3] = (j == 0) ? a3 : cmulc(a3, w16k<INV>(3*j));
    }
    #pragma unroll
    for (int q = 0; q < 4; ++q){
        cplx a0 = y[q], a1 = y[q+4], a2 = y[q+8], a3 = y[q+12];
        r4<INV>(a0, a1, a2, a3);
        x[q] = a0; x[q+4] = a1; x[q+8] = a2; x[q+12] = a3;
    }
}
template<bool INV>
__device__ __forceinline__ void dft6(cplx x[6]){
    cplx y[6];
    { cplx a0 = x[0], a1 = x[2], a2 = x[4]; r3<INV>(a0, a1, a2); y[0] = a0; y[1] = a1; y[2] = a2; }
    { cplx a0 = x[1], a1 = x[3], a2 = x[5]; r3<INV>(a0, a1, a2);
      y[3] = a0; y[4] = cmulc(a1, w6k<INV>(1)); y[5] = cmulc(a2, w6k<INV>(2)); }
    #pragma unroll
    for (int q = 0; q < 3; ++q){
        cplx s = caddc(y[q], y[q+3]), d = csubc(y[q], y[q+3]);
        x[q] = s; x[q+3] = d;
    }
}

template<int NW>
__device__ inline float block_reduce(float v){
    #pragma unroll
    for (int o = 32; o >= 1; o >>= 1) v += __shfl_down(v, o, 64);
    __shared__ float sh[NW];
    const int lane = threadIdx.x & 63, wv = threadIdx.x >> 6;
    if (lane == 0) sh[wv] = v;
    __syncthreads();
    float s = 0.f;
    if (threadIdx.x == 0){
        #pragma unroll
        for (int w = 0; w < NW; ++w) s += sh[w];
    }
    return s;
}

// ---------------------------------------------------------------------------
// K1: coil = csh*ph (fp16 in), padded row FFT 96->288 via DIF 6x16.
// Products register-cached across the 3 a-slices; 256-B aligned g bursts.
// ---------------------------------------------------------------------------
__global__ __launch_bounds__(512, 4)
void k_fwd(const gpak* __restrict__ ph, const gpak* __restrict__ csh,
           gpak* __restrict__ g, int cg0, int ncg, int ncga)
{
    __shared__ cplx A[NR * TILE];
    const int tid = threadIdx.x, bid = blockIdx.x;
    const int tile = bid % TILES;
    const int rem = bid / TILES;
    const int gc = rem % ncg, b = rem / ncg, c = cg0 + gc;
    const int colbase = tile * TILE;
    const gpak* pp = ph  + (size_t)b * NVOX;
    const gpak* cs = csh + ((size_t)b * C_ + c) * NVOX;
    gpak* gg = g + (size_t)(b * ncga + gc) * ((size_t)NP * NCOL);

    cplx xr[2][6];
    #pragma unroll
    for (int it = 0; it < 2; ++it){
        const int id = tid + it * 512;
        const int m = id >> 6, col = id & 63;
        #pragma unroll
        for (int v = 0; v < 6; ++v){
            const int gi = (m + 16*v) * NCOL + colbase + col;
            xr[it][v] = cmulc(unpack_g(pp[gi]), unpack_g(cs[gi]));
        }
    }

    for (int a = 0; a < 3; ++a){
        if (a) __syncthreads();
        #pragma unroll
        for (int it = 0; it < 2; ++it){
            const int id = tid + it * 512;
            const int m = id >> 6, col = id & 63;
            cplx xv[6];
            if (a){
                cplx t = twf((float)(a*m), R288);
                const cplx stp = twf((float)(16*a), R288);
                #pragma unroll
                for (int v = 0; v < 6; ++v){ xv[v] = cmulc(xr[it][v], t); t = cmulc(t, stp); }
            } else {
                #pragma unroll
                for (int v = 0; v < 6; ++v) xv[v] = xr[it][v];
            }
            dft6<false>(xv);
            cplx* dst = &A[m * TILE + col];
            dst[0] = xv[0];
            const cplx w1 = twf((float)m, R96);
            cplx t = w1;
            #pragma unroll
            for (int r = 1; r < 6; ++r){ dst[16*r*TILE] = cmulc(xv[r], t); t = cmulc(t, w1); }
        }
        __syncthreads();
        if (tid < 384){
            const int r = tid >> 6, col = tid & 63;
            cplx d[16];
            #pragma unroll
            for (int m = 0; m < 16; ++m) d[m] = A[(m + 16*r) * TILE + col];
            dft16<false>(d);
            const cplx pref = twf((float)(32*a), R96);   // e^{-2pi i a/3}
            #pragma unroll
            for (int t = 0; t < 16; ++t)
                gg[(size_t)(18*t + 3*r + a) * NCOL + colbase + col] = pack_g(cmulc(d[t], pref));
        }
    }
}

// ---------------------------------------------------------------------------
// K2: per padded row: g <- conj(w) * IFFT2( pm * FFT2( w*g ) ), DIF->DIT,
// permuted fp16 mask, in-place passes, turnaround fused in registers.
// ---------------------------------------------------------------------------
__global__ __launch_bounds__(512, 4)
void k_plane(gpak* __restrict__ g, const gpak* __restrict__ wh,
             const __half* __restrict__ pmh, int ncg, int ncga)
{
    __shared__ cplx A[NC_ * LSTR];
    const int tid = threadIdx.x, bid = blockIdx.x;
    const int rp = bid % NP;
    const int rem = bid / NP;
    const int gc = rem % ncg, b = rem / ncg;
    gpak* gg = g + ((size_t)(b * ncga + gc) * NP + rp) * NCOL;
    const gpak*  wp  = wh  + ((size_t)b * NP + rp) * NCOL;
    const __half* pmv = pmh + ((size_t)b * NP + rp) * NCOL;

    // ph1: ns DIF p1 (radix-3) from global, x w
    #pragma unroll
    for (int it = 0; it < 3; ++it){
        const int id = tid + it * 512;
        const int m = id & 15, nc = id >> 4;
        cplx xv[3];
        #pragma unroll
        for (int v = 0; v < 3; ++v){
            const int e = nc * NS + m + 16*v;
            xv[v] = cmulc(unpack_g(gg[e]), unpack_g(wp[e]));
        }
        r3<false>(xv[0], xv[1], xv[2]);
        cplx* dst = &A[nc * LSTR + m];
        const cplx w1 = twf((float)m, R48);
        dst[0]  = xv[0];
        dst[16] = cmulc(xv[1], w1);
        dst[32] = cmulc(xv[2], cmulc(w1, w1));
    }
    __syncthreads();
    // ph2: ns DIF p2 (radix-16, contiguous, in place)
    if (tid < 288){
        const int rho = tid / 96, nc = tid - rho * 96;
        cplx* pA = &A[nc * LSTR + 16 * rho];
        cplx d[16];
        #pragma unroll
        for (int m = 0; m < 16; ++m) d[m] = pA[m];
        dft16<false>(d);
        #pragma unroll
        for (int t = 0; t < 16; ++t) pA[t] = d[t];
    }
    __syncthreads();
    // ph3: nc DIF p1 (radix-6, in place)
    #pragma unroll
    for (int it = 0; it < 2; ++it){
        const int id = tid + it * 512;
        if (id < 768){
            const int m = id / NS, ns = id - m * NS;
            cplx xv[6];
            #pragma unroll
            for (int v = 0; v < 6; ++v) xv[v] = A[(m + 16*v) * LSTR + ns];
            dft6<false>(xv);
            const cplx w1 = twf((float)m, R96);
            A[m * LSTR + ns] = xv[0];
            cplx t = w1;
            #pragma unroll
            for (int r = 1; r < 6; ++r){ A[(m + 16*r) * LSTR + ns] = cmulc(xv[r], t); t = cmulc(t, w1); }
        }
    }
    __syncthreads();
    // ph4: nc DIF p2 + permuted mask + nc DIT p2 — in registers
    if (tid < 288){
        const int r = tid / NS, ns = tid - r * NS;
        cplx d[16];
        #pragma unroll
        for (int m = 0; m < 16; ++m) d[m] = A[(m + 16*r) * LSTR + ns];
        dft16<false>(d);
        #pragma unroll
        for (int t = 0; t < 16; ++t){
            const float mval = __half2float(pmv[(6*t + r) * NS + ns]);
            d[t].x *= mval; d[t].y *= mval;
        }
        dft16<true>(d);
        #pragma unroll
        for (int m = 0; m < 16; ++m) A[(m + 16*r) * LSTR + ns] = d[m];
    }
    __syncthreads();
    // ph5: nc DIT p1 (undo radix-6, in place)
    #pragma unroll
    for (int it = 0; it < 2; ++it){
        const int id = tid + it * 512;
        if (id < 768){
            const int m = id / NS, ns = id - m * NS;
            cplx xv[6];
            const cplx w1 = twf(-(float)m, R96);
            cplx t = make_float2(1.f, 0.f);
            #pragma unroll
            for (int r = 0; r < 6; ++r){ xv[r] = cmulc(A[(m + 16*r) * LSTR + ns], t); t = cmulc(t, w1); }
            dft6<true>(xv);
            #pragma unroll
            for (int v = 0; v < 6; ++v) A[(m + 16*v) * LSTR + ns] = xv[v];
        }
    }
    __syncthreads();
    // ph6: ns DIT p2 (idft16 contiguous, in place)
    if (tid < 288){
        const int rho = tid / 96, nc = tid - rho * 96;
        cplx* pA = &A[nc * LSTR + 16 * rho];
        cplx d[16];
        #pragma unroll
        for (int t = 0; t < 16; ++t) d[t] = pA[t];
        dft16<true>(d);
        #pragma unroll
        for (int m = 0; m < 16; ++m) pA[m] = d[m];
    }
    __syncthreads();
    // ph7: ns DIT p1 (undo radix-3) x conj(w), store fp16
    #pragma unroll
    for (int it = 0; it < 3; ++it){
        const int id = tid + it * 512;
        const int m = id & 15, nc = id >> 4;
        const cplx w1 = twf(-(float)m, R48);
        cplx xv[3];
        xv[0] = A[nc * LSTR + m];
        xv[1] = cmulc(A[nc * LSTR + m + 16], w1);
        xv[2] = cmulc(A[nc * LSTR + m + 32], cmulc(w1, w1));
        r3<true>(xv[0], xv[1], xv[2]);
        #pragma unroll
        for (int v = 0; v < 3; ++v){
            const int e = nc * NS + m + 16*v;
            gg[e] = pack_g(cmuljc(xv[v], unpack_g(wp[e])));
        }
    }
}

// ---------------------------------------------------------------------------
// K3: row IFFT 288->96 (crop) via DIT 16x6 per a-slice, 2 coils per block;
// conj(csm) folded in; block OWNS its ap-slice tile -> plain stores, NO atomics.
// ---------------------------------------------------------------------------
__global__ __launch_bounds__(512, 3)
void k_inv(const gpak* __restrict__ g, const gpak* __restrict__ csh,
           const gpak* __restrict__ ph, cplx* __restrict__ ap,
           float* __restrict__ sc, int cg0, int ncg, int ng, int ncga, int iter)
{
    __shared__ cplx A[NR * TILE];
    const int tid = threadIdx.x, bid = blockIdx.x;
    const int tile = bid % TILES;
    const int rem = bid / TILES;
    const int gl = rem % ng, b = rem / ng;
    const int cbase = cg0 + gl * CPB;
    const int slice = cbase / CPB;      // 0..5 across both chains
    const int colbase = tile * TILE;

    cplx accT[2][6];
    #pragma unroll
    for (int it = 0; it < 2; ++it)
        #pragma unroll
        for (int j = 0; j < 6; ++j) accT[it][j] = make_float2(0.f, 0.f);

    bool first = true;
    for (int ci = 0; ci < CPB; ++ci){
        const int c = cbase + ci;
        const gpak* gc_ = g + (size_t)(b * ncga + (c - cg0)) * ((size_t)NP * NCOL);
        const gpak* cs  = csh + ((size_t)b * C_ + c) * NVOX;

        for (int a = 0; a < 3; ++a){
            if (!first) __syncthreads();
            first = false;
            if (tid < 384){
                const int c6 = tid >> 6, col = tid & 63;
                cplx d[16];
                #pragma unroll
                for (int u = 0; u < 16; ++u)
                    d[u] = unpack_g(gc_[(size_t)(3*(c6 + 6*u) + a) * NCOL + colbase + col]);
                dft16<true>(d);
                #pragma unroll
                for (int q = 0; q < 16; ++q) A[(c6 + 6*q) * TILE + col] = d[q];
            }
            __syncthreads();
            #pragma unroll
            for (int it = 0; it < 2; ++it){
                const int id = tid + it * 512;
                const int q = id >> 6, col = id & 63;
                cplx xv[6];
                const cplx w1 = twf(-(float)q, R96);
                cplx t = make_float2(1.f, 0.f);
                #pragma unroll
                for (int cc = 0; cc < 6; ++cc){ xv[cc] = cmulc(A[(cc + 6*q) * TILE + col], t); t = cmulc(t, w1); }
                dft6<true>(xv);
                cplx f = twf(-(float)(a * (q + 96)), R288);
                f.x *= (1.f/288.f); f.y *= (1.f/288.f);
                const cplx fs = twf(-(float)(16 * a), R288);
                #pragma unroll
                for (int j = 0; j < 6; ++j){
                    const int gi = (q + 16*j) * NCOL + colbase + col;
                    accT[it][j] = caddc(accT[it][j], cmuljc(cmulc(xv[j], f), unpack_g(cs[gi])));
                    f = cmulc(f, fs);
                }
            }
        }
    }
    // epilogue: plain stores into owned ap-slice tile + local pAp partial
    cplx* aps = ap + ((size_t)slice * B_ + b) * NVOX;
    const gpak* pb = ph + (size_t)b * NVOX;
    float dotloc = 0.f;
    #pragma unroll
    for (int it = 0; it < 2; ++it){
        const int id = tid + it * 512;
        const int q = id >> 6, col = id & 63;
        #pragma unroll
        for (int j = 0; j < 6; ++j){
            const int gi = (q + 16*j) * NCOL + colbase + col;
            aps[gi] = accT[it][j];
            const cplx pv = unpack_g(pb[gi]);
            dotloc += pv.x * accT[it][j].x + pv.y * accT[it][j].y;
        }
    }
    const float s = block_reduce<8>(dotloc);
    if (tid == 0) atomAddF(&sc[PAP(iter) + b], s);
}

// ---------------------------------------------------------------------------
// prep kernels (once per solve)
// ---------------------------------------------------------------------------
__global__ __launch_bounds__(512)
void k_prep_csm(const cplx* __restrict__ csm, gpak* __restrict__ csh, int n)
{
    for (int i = blockIdx.x * 512 + threadIdx.x; i < n; i += gridDim.x * 512)
        csh[i] = pack_g(csm[i]);
}

__global__ __launch_bounds__(512)
void k_prep_wm(const cplx* __restrict__ wpsf, const float* __restrict__ mask,
               gpak* __restrict__ wh, __half* __restrict__ pmh)
{
    const int bid = blockIdx.x;            // b*NP + rp
    const cplx*  wsrc = wpsf + (size_t)bid * NCOL;
    const float* mk   = mask + (size_t)bid * NCOL;
    gpak*   wdst = wh  + (size_t)bid * NCOL;
    __half* out  = pmh + (size_t)bid * NCOL;
    for (int e = threadIdx.x; e < NCOL; e += 512){
        wdst[e] = pack_g(wsrc[e]);
        const int knc = e / NS, pns = e - knc * NS;
        const int kns = 3 * (pns & 15) + (pns >> 4);
        out[e] = __float2half(mk[knc * NS + kns] * (1.f / 4608.f));
    }
}

// ---------------------------------------------------------------------------
// CG kernels
// ---------------------------------------------------------------------------
__global__ __launch_bounds__(256)
void k_rr0(const cplx* __restrict__ r, gpak* __restrict__ ph, float* __restrict__ sc)
{
    const int i = blockIdx.x * 256 + threadIdx.x;
    const int b = i / NVOX;
    const cplx rv = r[i];
    ph[i] = pack_g(rv);
    const float s = block_reduce<4>(rv.x*rv.x + rv.y*rv.y);
    if (threadIdx.x == 0){ atomAddF(&sc[RTR(0) + b], s); atomAddF(&sc[PN(0) + b], s); }
}

__global__ __launch_bounds__(256)
void k_update(cplx* __restrict__ x, cplx* __restrict__ r,
              const cplx* __restrict__ p, const cplx* __restrict__ ap,
              const float* __restrict__ lam1, float* __restrict__ sc, int it)
{
    const int i = blockIdx.x * 256 + threadIdx.x;
    const int b = i / NVOX;
    const int iv = i - b * NVOX;
    const float rtr = sc[RTR(it) + b];
    const bool act = rtr > 1e-5f;
    const float lam = lam1[0];
    const float alpha = rtr / (sc[PAP(it) + b] + lam * sc[PN(it) + b]);
    const cplx pv = p[i];
    cplx a = make_float2(lam * pv.x, lam * pv.y);
    #pragma unroll
    for (int gp = 0; gp < NSL; ++gp){
        const cplx t = ap[((size_t)gp * B_ + b) * NVOX + iv];
        a.x += t.x; a.y += t.y;
    }
    cplx rv = r[i];
    if (act){
        cplx xv = x[i];
        xv.x += alpha * pv.x; xv.y += alpha * pv.y;
        x[i] = xv;
        rv.x -= alpha * a.x; rv.y -= alpha * a.y;
        r[i] = rv;
    }
    const float s = block_reduce<4>(rv.x*rv.x + rv.y*rv.y);
    if (threadIdx.x == 0) atomAddF(&sc[RTR(it+1) + b], s);
}

__global__ __launch_bounds__(256)
void k_pupd(cplx* __restrict__ p, gpak* __restrict__ ph,
            const cplx* __restrict__ r, float* __restrict__ sc, int it)
{
    const int i = blockIdx.x * 256 + threadIdx.x;
    const int b = i / NVOX;
    const float rtr = sc[RTR(it) + b];
    const bool act = rtr > 1e-5f;
    cplx pv = p[i];
    float loc;
    if (act){
        const float be = sc[RTR(it+1) + b] / rtr;
        const cplx rv = r[i];
        const cplx pn = make_float2(rv.x + be * pv.x, rv.y + be * pv.y);
        p[i] = pn; ph[i] = pack_g(pn);
        loc = pn.x*pn.x + pn.y*pn.y;
    } else {
        loc = pv.x*pv.x + pv.y*pv.y;
    }
    const float s = block_reduce<4>(loc);
    if (threadIdx.x == 0) atomAddF(&sc[PN(it+1) + b], s);
}

// ---------------------------------------------------------------------------
extern "C" void kernel_launch(void* const* d_in, const int* in_sizes, int n_in,
                              void* d_out, int out_size, void* d_ws, size_t ws_size,
                              hipStream_t stream)
{
    const cplx*  rhs  = (const cplx*)d_in[0];
    const cplx*  csm  = (const cplx*)d_in[1];
    const float* mask = (const float*)d_in[2];
    const cplx*  wpsf = (const cplx*)d_in[3];
    const float* lam1 = (const float*)d_in[4];

    const size_t vb   = (size_t)B_ * NVOX * sizeof(cplx);           // 7,077,888 B
    const size_t hv   = (size_t)B_ * NVOX * sizeof(gpak);           // 3.5 MB
    const size_t pmb  = (size_t)B_ * NP * NCOL * sizeof(__half);    // 5.3 MB
    const size_t whb  = (size_t)B_ * NP * NCOL * sizeof(gpak);      // 10.6 MB
    const size_t cshb = (size_t)B_ * C_ * NVOX * sizeof(gpak);      // 42.5 MB
    const size_t percoil = (size_t)B_ * NP * NCOL * sizeof(gpak);   // 10.6 MB

    char* ws = (char*)d_ws;
    float* sc = (float*)ws;
    size_t off = 512;
    cplx* r    = (cplx*)(ws + off); off += vb;
    cplx* p    = (cplx*)(ws + off); off += vb;
    gpak* ph   = (gpak*)(ws + off); off += hv;
    __half* pmh = (__half*)(ws + off); off += pmb;
    cplx* ap   = (cplx*)(ws + off); off += (size_t)NSL * vb;
    gpak* csh  = (gpak*)(ws + off); off += cshb;
    gpak* wh   = (gpak*)(ws + off); off += whb;
    gpak* g    = (gpak*)(ws + off);
    cplx* x    = (cplx*)d_out;

    int ncga = CPB;
    if (ws_size > off){
        size_t fit = (ws_size - off) / percoil;
        ncga = fit > (size_t)NCGA_MAX ? NCGA_MAX : (int)fit;   // cap: keep chain LLC-resident
        ncga -= ncga % CPB;
        if (ncga < CPB) ncga = CPB;
    }

    hipMemsetAsync(d_out, 0, vb, stream);
    hipMemsetAsync(sc, 0, 512, stream);
    hipMemcpyAsync(r, rhs, vb, hipMemcpyDeviceToDevice, stream);
    hipMemcpyAsync(p, rhs, vb, hipMemcpyDeviceToDevice, stream);
    k_prep_csm<<<(B_ * C_ * NVOX) / 512, 512, 0, stream>>>(csm, csh, B_ * C_ * NVOX);
    k_prep_wm<<<B_ * NP, 512, 0, stream>>>(wpsf, mask, wh, pmh);
    k_rr0<<<(B_ * NVOX) / 256, 256, 0, stream>>>(r, ph, sc);

    for (int it = 0; it < 10; ++it){
        for (int cg0 = 0; cg0 < C_; cg0 += ncga){
            const int ncg = (C_ - cg0 < ncga) ? (C_ - cg0) : ncga;
            const int ng = ncg / CPB;
            k_fwd  <<<TILES * ncg * B_, 512, 0, stream>>>(ph, csh, g, cg0, ncg, ncga);
            k_plane<<<NP    * ncg * B_, 512, 0, stream>>>(g, wh, pmh, ncg, ncga);
            k_inv  <<<TILES * ng  * B_, 512, 0, stream>>>(g, csh, ph, ap, sc, cg0, ncg, ng, ncga, it);
        }
        k_update<<<(B_ * NVOX) / 256, 256, 0, stream>>>(x, r, p, ap, lam1, sc, it);
        k_pupd  <<<(B_ * NVOX) / 256, 256, 0, stream>>>(p, ph, r, sc, it);
    }
}

// Round 11
// 4278.539 us; speedup vs baseline: 1.6483x; 1.3797x over previous
//
#include <hip/hip_runtime.h>
#include <hip/hip_fp16.h>

typedef float2 cplx;
typedef __half2 gpak;   // packed complex fp16 (re, im)

constexpr int B_   = 2;
constexpr int C_   = 12;
constexpr int NR   = 96;
constexpr int NC_  = 96;
constexpr int NS   = 48;
constexpr int NP   = 288;
constexpr int NCOL = NC_ * NS;      // 4608
constexpr int NVOX = NR * NCOL;     // 442368
constexpr int HV   = NVOX / 2;      // cplx pairs per batch
constexpr int TILE = 64;            // cols per k_fwd/k_inv block (256-B bursts)
constexpr int TILES = NCOL / TILE;  // 72
constexpr int LSTR = 49;            // padded nc stride in k_plane LDS
constexpr int NSL  = C_;            // 12 fp16 ap slices (CPB=1)
constexpr float PI2 = 6.28318530717958647692f;
constexpr float R96 = 1.f/96.f, R48 = 1.f/48.f, R288 = 1.f/288.f;

// scalar slot map (floats, sc = 512 B)
#define RTR(it) (8 + 2*(it))
#define PAP(it) (32 + 2*(it))
#define PN(it)  (52 + 2*(it))

__device__ inline cplx cmulc(cplx a, cplx b){ return make_float2(a.x*b.x - a.y*b.y, a.x*b.y + a.y*b.x); }
__device__ inline cplx cmuljc(cplx a, cplx b){ return make_float2(a.x*b.x + a.y*b.y, a.y*b.x - a.x*b.y); }
__device__ inline cplx caddc(cplx a, cplx b){ return make_float2(a.x+b.x, a.y+b.y); }
__device__ inline cplx csubc(cplx a, cplx b){ return make_float2(a.x-b.x, a.y-b.y); }

__device__ __forceinline__ gpak pack_g(cplx v){ return __float22half2_rn(v); }
__device__ __forceinline__ cplx unpack_g(gpak h){ return __half22float2(h); }

union hpair { float2 f; gpak h[2]; };

__device__ inline void atomAddF(float* p, float v){
    __hip_atomic_fetch_add(p, v, __ATOMIC_RELAXED, __HIP_MEMORY_SCOPE_AGENT);
}

__device__ __forceinline__ cplx twf(float k, float rN){
    float s, c; __sincosf(-PI2 * k * rN, &s, &c);
    return make_float2(c, s);
}

// ---------------- register DFT cores ----------------
template<bool INV>
__device__ __forceinline__ cplx w16k(int k){
    constexpr float re[10] = {1.f, 0.92387953251f, 0.70710678119f, 0.38268343236f, 0.f,
                              -0.38268343236f, -0.70710678119f, -0.92387953251f, -1.f, -0.92387953251f};
    constexpr float im[10] = {0.f, -0.38268343236f, -0.70710678119f, -0.92387953251f, -1.f,
                              -0.92387953251f, -0.70710678119f, -0.38268343236f, 0.f, 0.38268343236f};
    return make_float2(re[k], INV ? -im[k] : im[k]);
}
template<bool INV>
__device__ __forceinline__ cplx w6k(int k){
    const float rr = (k == 1) ? 0.5f : -0.5f;
    const float ii = INV ? 0.86602540378f : -0.86602540378f;
    return make_float2(rr, ii);
}
template<bool INV>
__device__ __forceinline__ void r4(cplx& a0, cplx& a1, cplx& a2, cplx& a3){
    cplx t0 = caddc(a0, a2), t1 = csubc(a0, a2);
    cplx t2 = caddc(a1, a3), t3 = csubc(a1, a3);
    cplx it3 = INV ? make_float2(-t3.y, t3.x) : make_float2(t3.y, -t3.x);
    a0 = caddc(t0, t2); a1 = caddc(t1, it3);
    a2 = csubc(t0, t2); a3 = csubc(t1, it3);
}
template<bool INV>
__device__ __forceinline__ void r3(cplx& a0, cplx& a1, cplx& a2){
    cplx t1 = caddc(a1, a2), t2 = csubc(a1, a2);
    cplx m1 = make_float2(a0.x - 0.5f * t1.x, a0.y - 0.5f * t1.y);
    const float s3 = INV ? -0.8660254037844386f : 0.8660254037844386f;
    cplx b1 = make_float2(m1.x + s3 * t2.y, m1.y - s3 * t2.x);
    cplx b2 = make_float2(m1.x - s3 * t2.y, m1.y + s3 * t2.x);
    a0 = caddc(a0, t1); a1 = b1; a2 = b2;
}
template<bool INV>
__device__ __forceinline__ void dft16(cplx x[16]){
    cplx y[16];
    #pragma unroll
    for (int j = 0; j < 4; ++j){
        cplx a0 = x[j], a1 = x[j+4], a2 = x[j+8], a3 = x[j+12];
        r4<INV>(a0, a1, a2, a3);
        y[4*j+0] = a0;
        y[4*j+1] = (j == 0) ? a1 : cmulc(a1, w16k<INV>(j));
        y[4*j+2] = (j == 0) ? a2 : cmulc(a2, w16k<INV>(2*j));
        y[4*j+3] = (j == 0) ? a3 : cmulc(a3, w16k<INV>(3*j));
    }
    #pragma unroll
    for (int q = 0; q < 4; ++q){
        cplx a0 = y[q], a1 = y[q+4], a2 = y[q+8], a3 = y[q+12];
        r4<INV>(a0, a1, a2, a3);
        x[q] = a0; x[q+4] = a1; x[q+8] = a2; x[q+12] = a3;
    }
}
template<bool INV>
__device__ __forceinline__ void dft6(cplx x[6]){
    cplx y[6];
    { cplx a0 = x[0], a1 = x[2], a2 = x[4]; r3<INV>(a0, a1, a2); y[0] = a0; y[1] = a1; y[2] = a2; }
    { cplx a0 = x[1], a1 = x[3], a2 = x[5]; r3<INV>(a0, a1, a2);
      y[3] = a0; y[4] = cmulc(a1, w6k<INV>(1)); y[5] = cmulc(a2, w6k<INV>(2)); }
    #pragma unroll
    for (int q = 0; q < 3; ++q){
        cplx s = caddc(y[q], y[q+3]), d = csubc(y[q], y[q+3]);
        x[q] = s; x[q+3] = d;
    }
}

template<int NW>
__device__ inline float block_reduce(float v){
    #pragma unroll
    for (int o = 32; o >= 1; o >>= 1) v += __shfl_down(v, o, 64);
    __shared__ float sh[NW];
    const int lane = threadIdx.x & 63, wv = threadIdx.x >> 6;
    if (lane == 0) sh[wv] = v;
    __syncthreads();
    float s = 0.f;
    if (threadIdx.x == 0){
        #pragma unroll
        for (int w = 0; w < NW; ++w) s += sh[w];
    }
    return s;
}

// ---------------------------------------------------------------------------
// K1: coil = csh*ph (fp16 in), padded row FFT 96->288 via DIF 6x16.
// Products register-cached across the 3 a-slices; 256-B aligned g bursts.
// ---------------------------------------------------------------------------
__global__ __launch_bounds__(512, 4)
void k_fwd(const gpak* __restrict__ ph, const gpak* __restrict__ csh,
           gpak* __restrict__ g, int cg0, int ncg, int ncga)
{
    __shared__ cplx A[NR * TILE];
    const int tid = threadIdx.x, bid = blockIdx.x;
    const int tile = bid % TILES;
    const int rem = bid / TILES;
    const int gc = rem % ncg, b = rem / ncg, c = cg0 + gc;
    const int colbase = tile * TILE;
    const gpak* pp = ph  + (size_t)b * NVOX;
    const gpak* cs = csh + ((size_t)b * C_ + c) * NVOX;
    gpak* gg = g + (size_t)(b * ncga + gc) * ((size_t)NP * NCOL);

    cplx xr[2][6];
    #pragma unroll
    for (int it = 0; it < 2; ++it){
        const int id = tid + it * 512;
        const int m = id >> 6, col = id & 63;
        #pragma unroll
        for (int v = 0; v < 6; ++v){
            const int gi = (m + 16*v) * NCOL + colbase + col;
            xr[it][v] = cmulc(unpack_g(pp[gi]), unpack_g(cs[gi]));
        }
    }

    for (int a = 0; a < 3; ++a){
        if (a) __syncthreads();
        #pragma unroll
        for (int it = 0; it < 2; ++it){
            const int id = tid + it * 512;
            const int m = id >> 6, col = id & 63;
            cplx xv[6];
            if (a){
                cplx t = twf((float)(a*m), R288);
                const cplx stp = twf((float)(16*a), R288);
                #pragma unroll
                for (int v = 0; v < 6; ++v){ xv[v] = cmulc(xr[it][v], t); t = cmulc(t, stp); }
            } else {
                #pragma unroll
                for (int v = 0; v < 6; ++v) xv[v] = xr[it][v];
            }
            dft6<false>(xv);
            cplx* dst = &A[m * TILE + col];
            dst[0] = xv[0];
            const cplx w1 = twf((float)m, R96);
            cplx t = w1;
            #pragma unroll
            for (int r = 1; r < 6; ++r){ dst[16*r*TILE] = cmulc(xv[r], t); t = cmulc(t, w1); }
        }
        __syncthreads();
        if (tid < 384){
            const int r = tid >> 6, col = tid & 63;
            cplx d[16];
            #pragma unroll
            for (int m = 0; m < 16; ++m) d[m] = A[(m + 16*r) * TILE + col];
            dft16<false>(d);
            const cplx pref = twf((float)(32*a), R96);   // e^{-2pi i a/3}
            #pragma unroll
            for (int t = 0; t < 16; ++t)
                gg[(size_t)(18*t + 3*r + a) * NCOL + colbase + col] = pack_g(cmulc(d[t], pref));
        }
    }
}

// ---------------------------------------------------------------------------
// K2: per padded row: g <- conj(w) * IFFT2( pm * FFT2( w*g ) ), DIF->DIT,
// permuted fp16 mask, in-place passes, turnaround fused in registers.
// ---------------------------------------------------------------------------
__global__ __launch_bounds__(512, 4)
void k_plane(gpak* __restrict__ g, const gpak* __restrict__ wh,
             const __half* __restrict__ pmh, int ncg, int ncga)
{
    __shared__ cplx A[NC_ * LSTR];
    const int tid = threadIdx.x, bid = blockIdx.x;
    const int rp = bid % NP;
    const int rem = bid / NP;
    const int gc = rem % ncg, b = rem / ncg;
    gpak* gg = g + ((size_t)(b * ncga + gc) * NP + rp) * NCOL;
    const gpak*  wp  = wh  + ((size_t)b * NP + rp) * NCOL;
    const __half* pmv = pmh + ((size_t)b * NP + rp) * NCOL;

    // ph1: ns DIF p1 (radix-3) from global, x w
    #pragma unroll
    for (int it = 0; it < 3; ++it){
        const int id = tid + it * 512;
        const int m = id & 15, nc = id >> 4;
        cplx xv[3];
        #pragma unroll
        for (int v = 0; v < 3; ++v){
            const int e = nc * NS + m + 16*v;
            xv[v] = cmulc(unpack_g(gg[e]), unpack_g(wp[e]));
        }
        r3<false>(xv[0], xv[1], xv[2]);
        cplx* dst = &A[nc * LSTR + m];
        const cplx w1 = twf((float)m, R48);
        dst[0]  = xv[0];
        dst[16] = cmulc(xv[1], w1);
        dst[32] = cmulc(xv[2], cmulc(w1, w1));
    }
    __syncthreads();
    // ph2: ns DIF p2 (radix-16, contiguous, in place)
    if (tid < 288){
        const int rho = tid / 96, nc = tid - rho * 96;
        cplx* pA = &A[nc * LSTR + 16 * rho];
        cplx d[16];
        #pragma unroll
        for (int m = 0; m < 16; ++m) d[m] = pA[m];
        dft16<false>(d);
        #pragma unroll
        for (int t = 0; t < 16; ++t) pA[t] = d[t];
    }
    __syncthreads();
    // ph3: nc DIF p1 (radix-6, in place)
    #pragma unroll
    for (int it = 0; it < 2; ++it){
        const int id = tid + it * 512;
        if (id < 768){
            const int m = id / NS, ns = id - m * NS;
            cplx xv[6];
            #pragma unroll
            for (int v = 0; v < 6; ++v) xv[v] = A[(m + 16*v) * LSTR + ns];
            dft6<false>(xv);
            const cplx w1 = twf((float)m, R96);
            A[m * LSTR + ns] = xv[0];
            cplx t = w1;
            #pragma unroll
            for (int r = 1; r < 6; ++r){ A[(m + 16*r) * LSTR + ns] = cmulc(xv[r], t); t = cmulc(t, w1); }
        }
    }
    __syncthreads();
    // ph4: nc DIF p2 + permuted mask + nc DIT p2 — in registers
    if (tid < 288){
        const int r = tid / NS, ns = tid - r * NS;
        cplx d[16];
        #pragma unroll
        for (int m = 0; m < 16; ++m) d[m] = A[(m + 16*r) * LSTR + ns];
        dft16<false>(d);
        #pragma unroll
        for (int t = 0; t < 16; ++t){
            const float mval = __half2float(pmv[(6*t + r) * NS + ns]);
            d[t].x *= mval; d[t].y *= mval;
        }
        dft16<true>(d);
        #pragma unroll
        for (int m = 0; m < 16; ++m) A[(m + 16*r) * LSTR + ns] = d[m];
    }
    __syncthreads();
    // ph5: nc DIT p1 (undo radix-6, in place)
    #pragma unroll
    for (int it = 0; it < 2; ++it){
        const int id = tid + it * 512;
        if (id < 768){
            const int m = id / NS, ns = id - m * NS;
            cplx xv[6];
            const cplx w1 = twf(-(float)m, R96);
            cplx t = make_float2(1.f, 0.f);
            #pragma unroll
            for (int r = 0; r < 6; ++r){ xv[r] = cmulc(A[(m + 16*r) * LSTR + ns], t); t = cmulc(t, w1); }
            dft6<true>(xv);
            #pragma unroll
            for (int v = 0; v < 6; ++v) A[(m + 16*v) * LSTR + ns] = xv[v];
        }
    }
    __syncthreads();
    // ph6: ns DIT p2 (idft16 contiguous, in place)
    if (tid < 288){
        const int rho = tid / 96, nc = tid - rho * 96;
        cplx* pA = &A[nc * LSTR + 16 * rho];
        cplx d[16];
        #pragma unroll
        for (int t = 0; t < 16; ++t) d[t] = pA[t];
        dft16<true>(d);
        #pragma unroll
        for (int m = 0; m < 16; ++m) pA[m] = d[m];
    }
    __syncthreads();
    // ph7: ns DIT p1 (undo radix-3) x conj(w), store fp16
    #pragma unroll
    for (int it = 0; it < 3; ++it){
        const int id = tid + it * 512;
        const int m = id & 15, nc = id >> 4;
        const cplx w1 = twf(-(float)m, R48);
        cplx xv[3];
        xv[0] = A[nc * LSTR + m];
        xv[1] = cmulc(A[nc * LSTR + m + 16], w1);
        xv[2] = cmulc(A[nc * LSTR + m + 32], cmulc(w1, w1));
        r3<true>(xv[0], xv[1], xv[2]);
        #pragma unroll
        for (int v = 0; v < 3; ++v){
            const int e = nc * NS + m + 16*v;
            gg[e] = pack_g(cmuljc(xv[v], unpack_g(wp[e])));
        }
    }
}

// ---------------------------------------------------------------------------
// K3: row IFFT 288->96 (crop) via DIT 16x6 per a-slice, ONE coil per block;
// conj(csm) folded in; block OWNS its fp16 ap-slice tile -> plain stores.
// ---------------------------------------------------------------------------
__global__ __launch_bounds__(512, 3)
void k_inv(const gpak* __restrict__ g, const gpak* __restrict__ csh,
           const gpak* __restrict__ ph, gpak* __restrict__ ap,
           float* __restrict__ sc, int cg0, int ncg, int ncga, int iter)
{
    __shared__ cplx A[NR * TILE];
    const int tid = threadIdx.x, bid = blockIdx.x;
    const int tile = bid % TILES;
    const int rem = bid / TILES;
    const int gc = rem % ncg, b = rem / ncg;
    const int c = cg0 + gc;
    const int slice = c;                 // 0..11
    const int colbase = tile * TILE;

    const gpak* gc_ = g + (size_t)(b * ncga + gc) * ((size_t)NP * NCOL);
    const gpak* cs  = csh + ((size_t)b * C_ + c) * NVOX;

    cplx accT[2][6];
    #pragma unroll
    for (int it = 0; it < 2; ++it)
        #pragma unroll
        for (int j = 0; j < 6; ++j) accT[it][j] = make_float2(0.f, 0.f);

    for (int a = 0; a < 3; ++a){
        if (a) __syncthreads();
        if (tid < 384){
            const int c6 = tid >> 6, col = tid & 63;
            cplx d[16];
            #pragma unroll
            for (int u = 0; u < 16; ++u)
                d[u] = unpack_g(gc_[(size_t)(3*(c6 + 6*u) + a) * NCOL + colbase + col]);
            dft16<true>(d);
            #pragma unroll
            for (int q = 0; q < 16; ++q) A[(c6 + 6*q) * TILE + col] = d[q];
        }
        __syncthreads();
        #pragma unroll
        for (int it = 0; it < 2; ++it){
            const int id = tid + it * 512;
            const int q = id >> 6, col = id & 63;
            cplx xv[6];
            const cplx w1 = twf(-(float)q, R96);
            cplx t = make_float2(1.f, 0.f);
            #pragma unroll
            for (int cc = 0; cc < 6; ++cc){ xv[cc] = cmulc(A[(cc + 6*q) * TILE + col], t); t = cmulc(t, w1); }
            dft6<true>(xv);
            cplx f = twf(-(float)(a * (q + 96)), R288);
            f.x *= (1.f/288.f); f.y *= (1.f/288.f);
            const cplx fs = twf(-(float)(16 * a), R288);
            #pragma unroll
            for (int j = 0; j < 6; ++j){
                const int gi = (q + 16*j) * NCOL + colbase + col;
                accT[it][j] = caddc(accT[it][j], cmuljc(cmulc(xv[j], f), unpack_g(cs[gi])));
                f = cmulc(f, fs);
            }
        }
    }
    // epilogue: fp16 stores into owned ap-slice tile + fp32 pAp partial
    gpak* aps = ap + ((size_t)slice * B_ + b) * NVOX;
    const gpak* pb = ph + (size_t)b * NVOX;
    float dotloc = 0.f;
    #pragma unroll
    for (int it = 0; it < 2; ++it){
        const int id = tid + it * 512;
        const int q = id >> 6, col = id & 63;
        #pragma unroll
        for (int j = 0; j < 6; ++j){
            const int gi = (q + 16*j) * NCOL + colbase + col;
            aps[gi] = pack_g(accT[it][j]);
            const cplx pv = unpack_g(pb[gi]);
            dotloc += pv.x * accT[it][j].x + pv.y * accT[it][j].y;
        }
    }
    const float s = block_reduce<8>(dotloc);
    if (tid == 0) atomAddF(&sc[PAP(iter) + b], s);
}

// ---------------------------------------------------------------------------
// prep kernels (once per solve)
// ---------------------------------------------------------------------------
__global__ __launch_bounds__(512)
void k_prep_csm(const cplx* __restrict__ csm, gpak* __restrict__ csh, int n)
{
    for (int i = blockIdx.x * 512 + threadIdx.x; i < n; i += gridDim.x * 512)
        csh[i] = pack_g(csm[i]);
}

__global__ __launch_bounds__(512)
void k_prep_wm(const cplx* __restrict__ wpsf, const float* __restrict__ mask,
               gpak* __restrict__ wh, __half* __restrict__ pmh)
{
    const int bid = blockIdx.x;            // b*NP + rp
    const cplx*  wsrc = wpsf + (size_t)bid * NCOL;
    const float* mk   = mask + (size_t)bid * NCOL;
    gpak*   wdst = wh  + (size_t)bid * NCOL;
    __half* out  = pmh + (size_t)bid * NCOL;
    for (int e = threadIdx.x; e < NCOL; e += 512){
        wdst[e] = pack_g(wsrc[e]);
        const int knc = e / NS, pns = e - knc * NS;
        const int kns = 3 * (pns & 15) + (pns >> 4);
        out[e] = __float2half(mk[knc * NS + kns] * (1.f / 4608.f));
    }
}

// ---------------------------------------------------------------------------
// CG kernels (2 cplx per thread, vectorized)
// ---------------------------------------------------------------------------
__global__ __launch_bounds__(256)
void k_rr0(const cplx* __restrict__ r, gpak* __restrict__ ph, float* __restrict__ sc)
{
    const int i = blockIdx.x * 256 + threadIdx.x;
    const int b = i / NVOX;
    const cplx rv = r[i];
    ph[i] = pack_g(rv);
    const float s = block_reduce<4>(rv.x*rv.x + rv.y*rv.y);
    if (threadIdx.x == 0){ atomAddF(&sc[RTR(0) + b], s); atomAddF(&sc[PN(0) + b], s); }
}

__global__ __launch_bounds__(256)
void k_update(cplx* __restrict__ x, cplx* __restrict__ r,
              const cplx* __restrict__ p, const gpak* __restrict__ ap,
              const float* __restrict__ lam1, float* __restrict__ sc, int it)
{
    const int i2 = blockIdx.x * 256 + threadIdx.x;        // pair index
    const int b  = (int)(((size_t)blockIdx.x * 512) / NVOX);  // uniform per block
    const int j2 = i2 - b * HV;                           // pair index within batch
    const float rtr = sc[RTR(it) + b];
    const bool act = rtr > 1e-5f;
    const float lam = lam1[0];
    const float alpha = rtr / (sc[PAP(it) + b] + lam * sc[PN(it) + b]);

    const float4 pv4 = ((const float4*)p)[i2];
    cplx a0 = make_float2(lam * pv4.x, lam * pv4.y);
    cplx a1 = make_float2(lam * pv4.z, lam * pv4.w);
    #pragma unroll
    for (int gp = 0; gp < NSL; ++gp){
        hpair u;
        u.f = ((const float2*)(ap + ((size_t)gp * B_ + b) * NVOX))[j2];
        const cplx t0 = unpack_g(u.h[0]), t1 = unpack_g(u.h[1]);
        a0.x += t0.x; a0.y += t0.y;
        a1.x += t1.x; a1.y += t1.y;
    }
    float4 rv4 = ((const float4*)r)[i2];
    float loc = 0.f;
    if (act){
        float4 xv4 = ((const float4*)x)[i2];
        xv4.x += alpha * pv4.x; xv4.y += alpha * pv4.y;
        xv4.z += alpha * pv4.z; xv4.w += alpha * pv4.w;
        ((float4*)x)[i2] = xv4;
        rv4.x -= alpha * a0.x; rv4.y -= alpha * a0.y;
        rv4.z -= alpha * a1.x; rv4.w -= alpha * a1.y;
        ((float4*)r)[i2] = rv4;
    }
    loc = rv4.x*rv4.x + rv4.y*rv4.y + rv4.z*rv4.z + rv4.w*rv4.w;
    const float s = block_reduce<4>(loc);
    if (threadIdx.x == 0) atomAddF(&sc[RTR(it+1) + b], s);
}

__global__ __launch_bounds__(256)
void k_pupd(cplx* __restrict__ p, gpak* __restrict__ ph,
            const cplx* __restrict__ r, float* __restrict__ sc, int it)
{
    const int i2 = blockIdx.x * 256 + threadIdx.x;
    const int b  = (int)(((size_t)blockIdx.x * 512) / NVOX);
    const float rtr = sc[RTR(it) + b];
    const bool act = rtr > 1e-5f;
    const float4 pv4 = ((const float4*)p)[i2];
    float loc;
    if (act){
        const float be = sc[RTR(it+1) + b] / rtr;
        const float4 rv4 = ((const float4*)r)[i2];
        float4 pn4;
        pn4.x = rv4.x + be * pv4.x; pn4.y = rv4.y + be * pv4.y;
        pn4.z = rv4.z + be * pv4.z; pn4.w = rv4.w + be * pv4.w;
        ((float4*)p)[i2] = pn4;
        hpair u;
        u.h[0] = pack_g(make_float2(pn4.x, pn4.y));
        u.h[1] = pack_g(make_float2(pn4.z, pn4.w));
        ((float2*)ph)[i2] = u.f;
        loc = pn4.x*pn4.x + pn4.y*pn4.y + pn4.z*pn4.z + pn4.w*pn4.w;
    } else {
        loc = pv4.x*pv4.x + pv4.y*pv4.y + pv4.z*pv4.z + pv4.w*pv4.w;
    }
    const float s = block_reduce<4>(loc);
    if (threadIdx.x == 0) atomAddF(&sc[PN(it+1) + b], s);
}

// ---------------------------------------------------------------------------
extern "C" void kernel_launch(void* const* d_in, const int* in_sizes, int n_in,
                              void* d_out, int out_size, void* d_ws, size_t ws_size,
                              hipStream_t stream)
{
    const cplx*  rhs  = (const cplx*)d_in[0];
    const cplx*  csm  = (const cplx*)d_in[1];
    const float* mask = (const float*)d_in[2];
    const cplx*  wpsf = (const cplx*)d_in[3];
    const float* lam1 = (const float*)d_in[4];

    const size_t vb   = (size_t)B_ * NVOX * sizeof(cplx);           // 7,077,888 B
    const size_t hv   = (size_t)B_ * NVOX * sizeof(gpak);           // 3.5 MB
    const size_t pmb  = (size_t)B_ * NP * NCOL * sizeof(__half);    // 5.3 MB
    const size_t whb  = (size_t)B_ * NP * NCOL * sizeof(gpak);      // 10.6 MB
    const size_t cshb = (size_t)B_ * C_ * NVOX * sizeof(gpak);      // 42.5 MB
    const size_t percoil = (size_t)B_ * NP * NCOL * sizeof(gpak);   // 10.6 MB

    char* ws = (char*)d_ws;
    float* sc = (float*)ws;
    size_t off = 512;
    cplx* r    = (cplx*)(ws + off); off += vb;
    cplx* p    = (cplx*)(ws + off); off += vb;
    gpak* ph   = (gpak*)(ws + off); off += hv;
    __half* pmh = (__half*)(ws + off); off += pmb;
    gpak* ap   = (gpak*)(ws + off); off += (size_t)NSL * hv;        // 42.5 MB fp16
    gpak* csh  = (gpak*)(ws + off); off += cshb;
    gpak* wh   = (gpak*)(ws + off); off += whb;
    gpak* g    = (gpak*)(ws + off);
    cplx* x    = (cplx*)d_out;

    int ncga = 1;
    if (ws_size > off){
        size_t fit = (ws_size - off) / percoil;
        ncga = fit > (size_t)C_ ? C_ : (int)fit;
        if (ncga < 1) ncga = 1;
    }

    hipMemsetAsync(d_out, 0, vb, stream);
    hipMemsetAsync(sc, 0, 512, stream);
    hipMemcpyAsync(r, rhs, vb, hipMemcpyDeviceToDevice, stream);
    hipMemcpyAsync(p, rhs, vb, hipMemcpyDeviceToDevice, stream);
    k_prep_csm<<<(B_ * C_ * NVOX) / 512, 512, 0, stream>>>(csm, csh, B_ * C_ * NVOX);
    k_prep_wm<<<B_ * NP, 512, 0, stream>>>(wpsf, mask, wh, pmh);
    k_rr0<<<(B_ * NVOX) / 256, 256, 0, stream>>>(r, ph, sc);

    for (int it = 0; it < 10; ++it){
        for (int cg0 = 0; cg0 < C_; cg0 += ncga){
            const int ncg = (C_ - cg0 < ncga) ? (C_ - cg0) : ncga;
            k_fwd  <<<TILES * ncg * B_, 512, 0, stream>>>(ph, csh, g, cg0, ncg, ncga);
            k_plane<<<NP    * ncg * B_, 512, 0, stream>>>(g, wh, pmh, ncg, ncga);
            k_inv  <<<TILES * ncg * B_, 512, 0, stream>>>(g, csh, ph, ap, sc, cg0, ncg, ncga, it);
        }
        k_update<<<(B_ * NVOX) / 512, 256, 0, stream>>>(x, r, p, ap, lam1, sc, it);
        k_pupd  <<<(B_ * NVOX) / 512, 256, 0, stream>>>(p, ph, r, sc, it);
    }
}

// Round 12
// 3564.408 us; speedup vs baseline: 1.9785x; 1.2004x over previous
//
#include <hip/hip_runtime.h>
#include <hip/hip_fp16.h>

typedef float2 cplx;
typedef __half2 gpak;   // packed complex fp16 (re, im)

constexpr int B_   = 2;
constexpr int C_   = 12;
constexpr int NR   = 96;
constexpr int NC_  = 96;
constexpr int NS   = 48;
constexpr int NP   = 288;
constexpr int NCOL = NC_ * NS;      // 4608
constexpr int NVOX = NR * NCOL;     // 442368
constexpr int HV   = NVOX / 2;      // cplx pairs per batch
constexpr int TILE = 64;            // cols per k_fwd/k_inv block (256-B bursts)
constexpr int TILES = NCOL / TILE;  // 72
constexpr int LSTR = 49;            // padded nc stride in k_plane LDS
constexpr int NSL  = C_;            // 12 fp16 ap slices (CPB=1)
constexpr float PI2 = 6.28318530717958647692f;
constexpr float R96 = 1.f/96.f, R48 = 1.f/48.f, R288 = 1.f/288.f;

// scalar slot map (floats, sc = 512 B)
#define RTR(it) (8 + 2*(it))
#define PAP(it) (32 + 2*(it))
#define PN(it)  (52 + 2*(it))

__device__ inline cplx cmulc(cplx a, cplx b){ return make_float2(a.x*b.x - a.y*b.y, a.x*b.y + a.y*b.x); }
__device__ inline cplx cmuljc(cplx a, cplx b){ return make_float2(a.x*b.x + a.y*b.y, a.y*b.x - a.x*b.y); }
__device__ inline cplx caddc(cplx a, cplx b){ return make_float2(a.x+b.x, a.y+b.y); }
__device__ inline cplx csubc(cplx a, cplx b){ return make_float2(a.x-b.x, a.y-b.y); }

__device__ __forceinline__ gpak pack_g(cplx v){ return __float22half2_rn(v); }
__device__ __forceinline__ cplx unpack_g(gpak h){ return __half22float2(h); }

union hpair { float2 f; gpak h[2]; };

__device__ inline void atomAddF(float* p, float v){
    __hip_atomic_fetch_add(p, v, __ATOMIC_RELAXED, __HIP_MEMORY_SCOPE_AGENT);
}

__device__ __forceinline__ cplx twf(float k, float rN){
    float s, c; __sincosf(-PI2 * k * rN, &s, &c);
    return make_float2(c, s);
}

// ---------------- register DFT cores ----------------
template<bool INV>
__device__ __forceinline__ cplx w16k(int k){
    constexpr float re[10] = {1.f, 0.92387953251f, 0.70710678119f, 0.38268343236f, 0.f,
                              -0.38268343236f, -0.70710678119f, -0.92387953251f, -1.f, -0.92387953251f};
    constexpr float im[10] = {0.f, -0.38268343236f, -0.70710678119f, -0.92387953251f, -1.f,
                              -0.92387953251f, -0.70710678119f, -0.38268343236f, 0.f, 0.38268343236f};
    return make_float2(re[k], INV ? -im[k] : im[k]);
}
template<bool INV>
__device__ __forceinline__ cplx w6k(int k){
    const float rr = (k == 1) ? 0.5f : -0.5f;
    const float ii = INV ? 0.86602540378f : -0.86602540378f;
    return make_float2(rr, ii);
}
template<bool INV>
__device__ __forceinline__ void r4(cplx& a0, cplx& a1, cplx& a2, cplx& a3){
    cplx t0 = caddc(a0, a2), t1 = csubc(a0, a2);
    cplx t2 = caddc(a1, a3), t3 = csubc(a1, a3);
    cplx it3 = INV ? make_float2(-t3.y, t3.x) : make_float2(t3.y, -t3.x);
    a0 = caddc(t0, t2); a1 = caddc(t1, it3);
    a2 = csubc(t0, t2); a3 = csubc(t1, it3);
}
template<bool INV>
__device__ __forceinline__ void r3(cplx& a0, cplx& a1, cplx& a2){
    cplx t1 = caddc(a1, a2), t2 = csubc(a1, a2);
    cplx m1 = make_float2(a0.x - 0.5f * t1.x, a0.y - 0.5f * t1.y);
    const float s3 = INV ? -0.8660254037844386f : 0.8660254037844386f;
    cplx b1 = make_float2(m1.x + s3 * t2.y, m1.y - s3 * t2.x);
    cplx b2 = make_float2(m1.x - s3 * t2.y, m1.y + s3 * t2.x);
    a0 = caddc(a0, t1); a1 = b1; a2 = b2;
}
template<bool INV>
__device__ __forceinline__ void dft16(cplx x[16]){
    cplx y[16];
    #pragma unroll
    for (int j = 0; j < 4; ++j){
        cplx a0 = x[j], a1 = x[j+4], a2 = x[j+8], a3 = x[j+12];
        r4<INV>(a0, a1, a2, a3);
        y[4*j+0] = a0;
        y[4*j+1] = (j == 0) ? a1 : cmulc(a1, w16k<INV>(j));
        y[4*j+2] = (j == 0) ? a2 : cmulc(a2, w16k<INV>(2*j));
        y[4*j+3] = (j == 0) ? a3 : cmulc(a3, w16k<INV>(3*j));
    }
    #pragma unroll
    for (int q = 0; q < 4; ++q){
        cplx a0 = y[q], a1 = y[q+4], a2 = y[q+8], a3 = y[q+12];
        r4<INV>(a0, a1, a2, a3);
        x[q] = a0; x[q+4] = a1; x[q+8] = a2; x[q+12] = a3;
    }
}
template<bool INV>
__device__ __forceinline__ void dft6(cplx x[6]){
    cplx y[6];
    { cplx a0 = x[0], a1 = x[2], a2 = x[4]; r3<INV>(a0, a1, a2); y[0] = a0; y[1] = a1; y[2] = a2; }
    { cplx a0 = x[1], a1 = x[3], a2 = x[5]; r3<INV>(a0, a1, a2);
      y[3] = a0; y[4] = cmulc(a1, w6k<INV>(1)); y[5] = cmulc(a2, w6k<INV>(2)); }
    #pragma unroll
    for (int q = 0; q < 3; ++q){
        cplx s = caddc(y[q], y[q+3]), d = csubc(y[q], y[q+3]);
        x[q] = s; x[q+3] = d;
    }
}

template<int NW>
__device__ inline float block_reduce(float v){
    #pragma unroll
    for (int o = 32; o >= 1; o >>= 1) v += __shfl_down(v, o, 64);
    __shared__ float sh[NW];
    const int lane = threadIdx.x & 63, wv = threadIdx.x >> 6;
    if (lane == 0) sh[wv] = v;
    __syncthreads();
    float s = 0.f;
    if (threadIdx.x == 0){
        #pragma unroll
        for (int w = 0; w < NW; ++w) s += sh[w];
    }
    return s;
}

// ---------------------------------------------------------------------------
// K1: coil = csh*ph (fp16 in), padded row FFT 96->288 via DIF 6x16.
// All twiddles from LDS tables (no sincos / power chains in the loop).
// ---------------------------------------------------------------------------
__global__ __launch_bounds__(512, 4)
void k_fwd(const gpak* __restrict__ ph, const gpak* __restrict__ csh,
           gpak* __restrict__ g, int cg0, int ncg, int ncga)
{
    __shared__ cplx A[NR * TILE];
    __shared__ cplx t96[96];
    __shared__ cplx t288[288];
    const int tid = threadIdx.x, bid = blockIdx.x;
    if (tid < 96) t96[tid] = twf((float)tid, R96);
    if (tid < 288) t288[tid] = twf((float)tid, R288);

    const int tile = bid % TILES;
    const int rem = bid / TILES;
    const int gc = rem % ncg, b = rem / ncg, c = cg0 + gc;
    const int colbase = tile * TILE;
    const gpak* pp = ph  + (size_t)b * NVOX;
    const gpak* cs = csh + ((size_t)b * C_ + c) * NVOX;
    gpak* gg = g + (size_t)(b * ncga + gc) * ((size_t)NP * NCOL);

    cplx xr[2][6];
    #pragma unroll
    for (int it = 0; it < 2; ++it){
        const int id = tid + it * 512;
        const int m = id >> 6, col = id & 63;
        #pragma unroll
        for (int v = 0; v < 6; ++v){
            const int gi = (m + 16*v) * NCOL + colbase + col;
            xr[it][v] = cmulc(unpack_g(pp[gi]), unpack_g(cs[gi]));
        }
    }
    __syncthreads();   // tables ready

    for (int a = 0; a < 3; ++a){
        if (a) __syncthreads();
        #pragma unroll
        for (int it = 0; it < 2; ++it){
            const int id = tid + it * 512;
            const int m = id >> 6, col = id & 63;
            cplx xv[6];
            if (a){
                #pragma unroll
                for (int v = 0; v < 6; ++v)
                    xv[v] = cmulc(xr[it][v], t288[a * (m + 16*v)]);   // <= 190 < 288
            } else {
                #pragma unroll
                for (int v = 0; v < 6; ++v) xv[v] = xr[it][v];
            }
            dft6<false>(xv);
            cplx* dst = &A[m * TILE + col];
            dst[0] = xv[0];
            #pragma unroll
            for (int r = 1; r < 6; ++r)
                dst[16*r*TILE] = cmulc(xv[r], t96[m * r]);            // <= 75 < 96
        }
        __syncthreads();
        if (tid < 384){
            const int r = tid >> 6, col = tid & 63;
            cplx d[16];
            #pragma unroll
            for (int m = 0; m < 16; ++m) d[m] = A[(m + 16*r) * TILE + col];
            dft16<false>(d);
            const cplx pref = t96[32 * a];   // e^{-2pi i a/3}
            #pragma unroll
            for (int t = 0; t < 16; ++t)
                gg[(size_t)(18*t + 3*r + a) * NCOL + colbase + col] = pack_g(cmulc(d[t], pref));
        }
    }
}

// ---------------------------------------------------------------------------
// K2: per padded row: g <- conj(w) * IFFT2( pm * FFT2( w*g ) ), DIF->DIT,
// permuted fp16 mask; twiddles from LDS tables (conj via y-negate).
// ---------------------------------------------------------------------------
__global__ __launch_bounds__(512, 4)
void k_plane(gpak* __restrict__ g, const gpak* __restrict__ wh,
             const __half* __restrict__ pmh, int ncg, int ncga)
{
    __shared__ cplx A[NC_ * LSTR];
    __shared__ cplx t96[96];
    __shared__ cplx t48[48];
    const int tid = threadIdx.x, bid = blockIdx.x;
    if (tid < 96) t96[tid] = twf((float)tid, R96);
    else if (tid >= 128 && tid < 176) t48[tid - 128] = twf((float)(tid - 128), R48);

    const int rp = bid % NP;
    const int rem = bid / NP;
    const int gc = rem % ncg, b = rem / ncg;
    gpak* gg = g + ((size_t)(b * ncga + gc) * NP + rp) * NCOL;
    const gpak*  wp  = wh  + ((size_t)b * NP + rp) * NCOL;
    const __half* pmv = pmh + ((size_t)b * NP + rp) * NCOL;
    __syncthreads();   // tables ready

    // ph1: ns DIF p1 (radix-3) from global, x w
    #pragma unroll
    for (int it = 0; it < 3; ++it){
        const int id = tid + it * 512;
        const int m = id & 15, nc = id >> 4;
        cplx xv[3];
        #pragma unroll
        for (int v = 0; v < 3; ++v){
            const int e = nc * NS + m + 16*v;
            xv[v] = cmulc(unpack_g(gg[e]), unpack_g(wp[e]));
        }
        r3<false>(xv[0], xv[1], xv[2]);
        cplx* dst = &A[nc * LSTR + m];
        dst[0]  = xv[0];
        dst[16] = cmulc(xv[1], t48[m]);
        dst[32] = cmulc(xv[2], t48[2*m]);
    }
    __syncthreads();
    // ph2: ns DIF p2 (radix-16, contiguous, in place)
    if (tid < 288){
        const int rho = tid / 96, nc = tid - rho * 96;
        cplx* pA = &A[nc * LSTR + 16 * rho];
        cplx d[16];
        #pragma unroll
        for (int m = 0; m < 16; ++m) d[m] = pA[m];
        dft16<false>(d);
        #pragma unroll
        for (int t = 0; t < 16; ++t) pA[t] = d[t];
    }
    __syncthreads();
    // ph3: nc DIF p1 (radix-6, in place)
    #pragma unroll
    for (int it = 0; it < 2; ++it){
        const int id = tid + it * 512;
        if (id < 768){
            const int m = id / NS, ns = id - m * NS;
            cplx xv[6];
            #pragma unroll
            for (int v = 0; v < 6; ++v) xv[v] = A[(m + 16*v) * LSTR + ns];
            dft6<false>(xv);
            A[m * LSTR + ns] = xv[0];
            #pragma unroll
            for (int r = 1; r < 6; ++r)
                A[(m + 16*r) * LSTR + ns] = cmulc(xv[r], t96[m * r]);
        }
    }
    __syncthreads();
    // ph4: nc DIF p2 + permuted mask + nc DIT p2 — in registers
    if (tid < 288){
        const int r = tid / NS, ns = tid - r * NS;
        cplx d[16];
        #pragma unroll
        for (int m = 0; m < 16; ++m) d[m] = A[(m + 16*r) * LSTR + ns];
        dft16<false>(d);
        #pragma unroll
        for (int t = 0; t < 16; ++t){
            const float mval = __half2float(pmv[(6*t + r) * NS + ns]);
            d[t].x *= mval; d[t].y *= mval;
        }
        dft16<true>(d);
        #pragma unroll
        for (int m = 0; m < 16; ++m) A[(m + 16*r) * LSTR + ns] = d[m];
    }
    __syncthreads();
    // ph5: nc DIT p1 (undo radix-6, in place)
    #pragma unroll
    for (int it = 0; it < 2; ++it){
        const int id = tid + it * 512;
        if (id < 768){
            const int m = id / NS, ns = id - m * NS;
            cplx xv[6];
            xv[0] = A[m * LSTR + ns];
            #pragma unroll
            for (int r = 1; r < 6; ++r){
                cplx w = t96[m * r]; w.y = -w.y;
                xv[r] = cmulc(A[(m + 16*r) * LSTR + ns], w);
            }
            dft6<true>(xv);
            #pragma unroll
            for (int v = 0; v < 6; ++v) A[(m + 16*v) * LSTR + ns] = xv[v];
        }
    }
    __syncthreads();
    // ph6: ns DIT p2 (idft16 contiguous, in place)
    if (tid < 288){
        const int rho = tid / 96, nc = tid - rho * 96;
        cplx* pA = &A[nc * LSTR + 16 * rho];
        cplx d[16];
        #pragma unroll
        for (int t = 0; t < 16; ++t) d[t] = pA[t];
        dft16<true>(d);
        #pragma unroll
        for (int m = 0; m < 16; ++m) pA[m] = d[m];
    }
    __syncthreads();
    // ph7: ns DIT p1 (undo radix-3) x conj(w), store fp16
    #pragma unroll
    for (int it = 0; it < 3; ++it){
        const int id = tid + it * 512;
        const int m = id & 15, nc = id >> 4;
        cplx w1 = t48[m];   w1.y = -w1.y;
        cplx w2 = t48[2*m]; w2.y = -w2.y;
        cplx xv[3];
        xv[0] = A[nc * LSTR + m];
        xv[1] = cmulc(A[nc * LSTR + m + 16], w1);
        xv[2] = cmulc(A[nc * LSTR + m + 32], w2);
        r3<true>(xv[0], xv[1], xv[2]);
        #pragma unroll
        for (int v = 0; v < 3; ++v){
            const int e = nc * NS + m + 16*v;
            gg[e] = pack_g(cmuljc(xv[v], unpack_g(wp[e])));
        }
    }
}

// ---------------------------------------------------------------------------
// K3: row IFFT 288->96 (crop) via DIT 16x6 per a-slice, ONE coil per block;
// conj(csm) folded in; fp16 ap-slice stores; table twiddles; 1/288 in epilogue.
// ---------------------------------------------------------------------------
__global__ __launch_bounds__(512, 3)
void k_inv(const gpak* __restrict__ g, const gpak* __restrict__ csh,
           const gpak* __restrict__ ph, gpak* __restrict__ ap,
           float* __restrict__ sc, int cg0, int ncg, int ncga, int iter)
{
    __shared__ cplx A[NR * TILE];
    __shared__ cplx t96[96];
    __shared__ cplx t288[288];
    const int tid = threadIdx.x, bid = blockIdx.x;
    if (tid < 96) t96[tid] = twf((float)tid, R96);
    if (tid < 288) t288[tid] = twf((float)tid, R288);

    const int tile = bid % TILES;
    const int rem = bid / TILES;
    const int gc = rem % ncg, b = rem / ncg;
    const int c = cg0 + gc;
    const int slice = c;                 // 0..11
    const int colbase = tile * TILE;

    const gpak* gc_ = g + (size_t)(b * ncga + gc) * ((size_t)NP * NCOL);
    const gpak* cs  = csh + ((size_t)b * C_ + c) * NVOX;

    cplx accT[2][6];
    #pragma unroll
    for (int it = 0; it < 2; ++it)
        #pragma unroll
        for (int j = 0; j < 6; ++j) accT[it][j] = make_float2(0.f, 0.f);
    __syncthreads();   // tables ready

    for (int a = 0; a < 3; ++a){
        if (a) __syncthreads();
        if (tid < 384){
            const int c6 = tid >> 6, col = tid & 63;
            cplx d[16];
            #pragma unroll
            for (int u = 0; u < 16; ++u)
                d[u] = unpack_g(gc_[(size_t)(3*(c6 + 6*u) + a) * NCOL + colbase + col]);
            dft16<true>(d);
            #pragma unroll
            for (int q = 0; q < 16; ++q) A[(c6 + 6*q) * TILE + col] = d[q];
        }
        __syncthreads();
        #pragma unroll
        for (int it = 0; it < 2; ++it){
            const int id = tid + it * 512;
            const int q = id >> 6, col = id & 63;
            cplx xv[6];
            xv[0] = A[(6*q) * TILE + col];
            #pragma unroll
            for (int cc = 1; cc < 6; ++cc){
                cplx w = t96[q * cc]; w.y = -w.y;
                xv[cc] = cmulc(A[(cc + 6*q) * TILE + col], w);
            }
            dft6<true>(xv);
            if (a == 0){
                #pragma unroll
                for (int j = 0; j < 6; ++j){
                    const int gi = (q + 16*j) * NCOL + colbase + col;
                    accT[it][j] = caddc(accT[it][j], cmuljc(xv[j], unpack_g(cs[gi])));
                }
            } else {
                int idx = a * (q + 96);          // <= 222
                const int stp = 16 * a;
                #pragma unroll
                for (int j = 0; j < 6; ++j){
                    const int gi = (q + 16*j) * NCOL + colbase + col;
                    cplx f = t288[idx]; f.y = -f.y;   // conj
                    accT[it][j] = caddc(accT[it][j], cmuljc(cmulc(xv[j], f), unpack_g(cs[gi])));
                    idx += stp; if (idx >= 288) idx -= 288;
                }
            }
        }
    }
    // epilogue: scale 1/288, fp16 stores into owned ap-slice tile + fp32 pAp partial
    gpak* aps = ap + ((size_t)slice * B_ + b) * NVOX;
    const gpak* pb = ph + (size_t)b * NVOX;
    const float s288 = 1.f / 288.f;
    float dotloc = 0.f;
    #pragma unroll
    for (int it = 0; it < 2; ++it){
        const int id = tid + it * 512;
        const int q = id >> 6, col = id & 63;
        #pragma unroll
        for (int j = 0; j < 6; ++j){
            const int gi = (q + 16*j) * NCOL + colbase + col;
            cplx av = accT[it][j];
            av.x *= s288; av.y *= s288;
            aps[gi] = pack_g(av);
            const cplx pv = unpack_g(pb[gi]);
            dotloc += pv.x * av.x + pv.y * av.y;
        }
    }
    const float s = block_reduce<8>(dotloc);
    if (tid == 0) atomAddF(&sc[PAP(iter) + b], s);
}

// ---------------------------------------------------------------------------
// prep kernels (once per solve)
// ---------------------------------------------------------------------------
__global__ __launch_bounds__(512)
void k_prep_csm(const cplx* __restrict__ csm, gpak* __restrict__ csh, int n)
{
    for (int i = blockIdx.x * 512 + threadIdx.x; i < n; i += gridDim.x * 512)
        csh[i] = pack_g(csm[i]);
}

__global__ __launch_bounds__(512)
void k_prep_wm(const cplx* __restrict__ wpsf, const float* __restrict__ mask,
               gpak* __restrict__ wh, __half* __restrict__ pmh)
{
    const int bid = blockIdx.x;            // b*NP + rp
    const cplx*  wsrc = wpsf + (size_t)bid * NCOL;
    const float* mk   = mask + (size_t)bid * NCOL;
    gpak*   wdst = wh  + (size_t)bid * NCOL;
    __half* out  = pmh + (size_t)bid * NCOL;
    for (int e = threadIdx.x; e < NCOL; e += 512){
        wdst[e] = pack_g(wsrc[e]);
        const int knc = e / NS, pns = e - knc * NS;
        const int kns = 3 * (pns & 15) + (pns >> 4);
        out[e] = __float2half(mk[knc * NS + kns] * (1.f / 4608.f));
    }
}

// ---------------------------------------------------------------------------
// CG kernels (2 cplx per thread, vectorized)
// ---------------------------------------------------------------------------
__global__ __launch_bounds__(256)
void k_rr0(const cplx* __restrict__ r, gpak* __restrict__ ph, float* __restrict__ sc)
{
    const int i = blockIdx.x * 256 + threadIdx.x;
    const int b = i / NVOX;
    const cplx rv = r[i];
    ph[i] = pack_g(rv);
    const float s = block_reduce<4>(rv.x*rv.x + rv.y*rv.y);
    if (threadIdx.x == 0){ atomAddF(&sc[RTR(0) + b], s); atomAddF(&sc[PN(0) + b], s); }
}

__global__ __launch_bounds__(256)
void k_update(cplx* __restrict__ x, cplx* __restrict__ r,
              const cplx* __restrict__ p, const gpak* __restrict__ ap,
              const float* __restrict__ lam1, float* __restrict__ sc, int it)
{
    const int i2 = blockIdx.x * 256 + threadIdx.x;        // pair index
    const int b  = (int)(((size_t)blockIdx.x * 512) / NVOX);  // uniform per block
    const int j2 = i2 - b * HV;                           // pair index within batch
    const float rtr = sc[RTR(it) + b];
    const bool act = rtr > 1e-5f;
    const float lam = lam1[0];
    const float alpha = rtr / (sc[PAP(it) + b] + lam * sc[PN(it) + b]);

    const float4 pv4 = ((const float4*)p)[i2];
    cplx a0 = make_float2(lam * pv4.x, lam * pv4.y);
    cplx a1 = make_float2(lam * pv4.z, lam * pv4.w);
    #pragma unroll
    for (int gp = 0; gp < NSL; ++gp){
        hpair u;
        u.f = ((const float2*)(ap + ((size_t)gp * B_ + b) * NVOX))[j2];
        const cplx t0 = unpack_g(u.h[0]), t1 = unpack_g(u.h[1]);
        a0.x += t0.x; a0.y += t0.y;
        a1.x += t1.x; a1.y += t1.y;
    }
    float4 rv4 = ((const float4*)r)[i2];
    float loc = 0.f;
    if (act){
        float4 xv4 = ((const float4*)x)[i2];
        xv4.x += alpha * pv4.x; xv4.y += alpha * pv4.y;
        xv4.z += alpha * pv4.z; xv4.w += alpha * pv4.w;
        ((float4*)x)[i2] = xv4;
        rv4.x -= alpha * a0.x; rv4.y -= alpha * a0.y;
        rv4.z -= alpha * a1.x; rv4.w -= alpha * a1.y;
        ((float4*)r)[i2] = rv4;
    }
    loc = rv4.x*rv4.x + rv4.y*rv4.y + rv4.z*rv4.z + rv4.w*rv4.w;
    const float s = block_reduce<4>(loc);
    if (threadIdx.x == 0) atomAddF(&sc[RTR(it+1) + b], s);
}

__global__ __launch_bounds__(256)
void k_pupd(cplx* __restrict__ p, gpak* __restrict__ ph,
            const cplx* __restrict__ r, float* __restrict__ sc, int it)
{
    const int i2 = blockIdx.x * 256 + threadIdx.x;
    const int b  = (int)(((size_t)blockIdx.x * 512) / NVOX);
    const float rtr = sc[RTR(it) + b];
    const bool act = rtr > 1e-5f;
    const float4 pv4 = ((const float4*)p)[i2];
    float loc;
    if (act){
        const float be = sc[RTR(it+1) + b] / rtr;
        const float4 rv4 = ((const float4*)r)[i2];
        float4 pn4;
        pn4.x = rv4.x + be * pv4.x; pn4.y = rv4.y + be * pv4.y;
        pn4.z = rv4.z + be * pv4.z; pn4.w = rv4.w + be * pv4.w;
        ((float4*)p)[i2] = pn4;
        hpair u;
        u.h[0] = pack_g(make_float2(pn4.x, pn4.y));
        u.h[1] = pack_g(make_float2(pn4.z, pn4.w));
        ((float2*)ph)[i2] = u.f;
        loc = pn4.x*pn4.x + pn4.y*pn4.y + pn4.z*pn4.z + pn4.w*pn4.w;
    } else {
        loc = pv4.x*pv4.x + pv4.y*pv4.y + pv4.z*pv4.z + pv4.w*pv4.w;
    }
    const float s = block_reduce<4>(loc);
    if (threadIdx.x == 0) atomAddF(&sc[PN(it+1) + b], s);
}

// ---------------------------------------------------------------------------
extern "C" void kernel_launch(void* const* d_in, const int* in_sizes, int n_in,
                              void* d_out, int out_size, void* d_ws, size_t ws_size,
                              hipStream_t stream)
{
    const cplx*  rhs  = (const cplx*)d_in[0];
    const cplx*  csm  = (const cplx*)d_in[1];
    const float* mask = (const float*)d_in[2];
    const cplx*  wpsf = (const cplx*)d_in[3];
    const float* lam1 = (const float*)d_in[4];

    const size_t vb   = (size_t)B_ * NVOX * sizeof(cplx);           // 7,077,888 B
    const size_t hv   = (size_t)B_ * NVOX * sizeof(gpak);           // 3.5 MB
    const size_t pmb  = (size_t)B_ * NP * NCOL * sizeof(__half);    // 5.3 MB
    const size_t whb  = (size_t)B_ * NP * NCOL * sizeof(gpak);      // 10.6 MB
    const size_t cshb = (size_t)B_ * C_ * NVOX * sizeof(gpak);      // 42.5 MB
    const size_t percoil = (size_t)B_ * NP * NCOL * sizeof(gpak);   // 10.6 MB

    char* ws = (char*)d_ws;
    float* sc = (float*)ws;
    size_t off = 512;
    cplx* r    = (cplx*)(ws + off); off += vb;
    cplx* p    = (cplx*)(ws + off); off += vb;
    gpak* ph   = (gpak*)(ws + off); off += hv;
    __half* pmh = (__half*)(ws + off); off += pmb;
    gpak* ap   = (gpak*)(ws + off); off += (size_t)NSL * hv;        // 42.5 MB fp16
    gpak* csh  = (gpak*)(ws + off); off += cshb;
    gpak* wh   = (gpak*)(ws + off); off += whb;
    gpak* g    = (gpak*)(ws + off);
    cplx* x    = (cplx*)d_out;

    int ncga = 1;
    if (ws_size > off){
        size_t fit = (ws_size - off) / percoil;
        ncga = fit > (size_t)C_ ? C_ : (int)fit;
        if (ncga < 1) ncga = 1;
    }

    hipMemsetAsync(d_out, 0, vb, stream);
    hipMemsetAsync(sc, 0, 512, stream);
    hipMemcpyAsync(r, rhs, vb, hipMemcpyDeviceToDevice, stream);
    hipMemcpyAsync(p, rhs, vb, hipMemcpyDeviceToDevice, stream);
    k_prep_csm<<<(B_ * C_ * NVOX) / 512, 512, 0, stream>>>(csm, csh, B_ * C_ * NVOX);
    k_prep_wm<<<B_ * NP, 512, 0, stream>>>(wpsf, mask, wh, pmh);
    k_rr0<<<(B_ * NVOX) / 256, 256, 0, stream>>>(r, ph, sc);

    for (int it = 0; it < 10; ++it){
        for (int cg0 = 0; cg0 < C_; cg0 += ncga){
            const int ncg = (C_ - cg0 < ncga) ? (C_ - cg0) : ncga;
            k_fwd  <<<TILES * ncg * B_, 512, 0, stream>>>(ph, csh, g, cg0, ncg, ncga);
            k_plane<<<NP    * ncg * B_, 512, 0, stream>>>(g, wh, pmh, ncg, ncga);
            k_inv  <<<TILES * ncg * B_, 512, 0, stream>>>(g, csh, ph, ap, sc, cg0, ncg, ncga, it);
        }
        k_update<<<(B_ * NVOX) / 512, 256, 0, stream>>>(x, r, p, ap, lam1, sc, it);
        k_pupd  <<<(B_ * NVOX) / 512, 256, 0, stream>>>(p, ph, r, sc, it);
    }
}